// Round 3
// baseline (508.900 us; speedup 1.0000x reference)
//
#include <hip/hip_runtime.h>

#define NPTS 8192
#define NB 4

// ---------------- fused-kernel configuration ----------------
#define WPB 4                               // waves per block
#define ITILES 8                            // 16-row MFMA tiles per wave
#define ROWS_PER_WAVE (ITILES * 16)         // 128
#define ROWS_PER_BLOCK (WPB * ROWS_PER_WAVE)// 512
#define CHUNK 512                           // cols per block
#define JT (CHUNK / 16)                     // 32 col tiles
#define CHUNKS (NPTS / CHUNK)               // 16
#define ROWBLKS (NPTS / ROWS_PER_BLOCK)     // 16

using bf16x8 = __attribute__((ext_vector_type(8))) short;
using f32x4  = __attribute__((ext_vector_type(4))) float;

// bf16 round-to-nearest-even, manual
__device__ __forceinline__ unsigned short bfb(float v) {
    unsigned int x = __float_as_uint(v);
    return (unsigned short)((x + 0x7FFFu + ((x >> 16) & 1u)) >> 16);
}
__device__ __forceinline__ float bff(unsigned short u) {
    return __uint_as_float(((unsigned int)u) << 16);
}
// 3-way bf16 split: v ~= H + M + L (captures full fp32 mantissa)
__device__ __forceinline__ void split3(float v, unsigned short& H,
                                       unsigned short& M, unsigned short& L) {
    H = bfb(v); float r = v - bff(H);
    M = bfb(r); L = bfb(r - bff(M));
}

// ---------------------------------------------------------------------------
// 2x2 tile group: 16 MFMAs, min3-paired reductions (~1 VALU op per element).
// Col partials: collapse cp[4] -> 1, shfl_xor over hi-groups, 16-lane
// distinct-address LDS atomicMin (contention across waves only).
// Encode math (HW-verified rounds 1-2): dot(Arow(p), Bcol(t)) ==
// |p|^2 - 2 p.t + |t|^2 to ~1e-6 via 3-way bf16 split, K=24 of 32 slots.
// ---------------------------------------------------------------------------
__device__ __forceinline__ void tile_pair(
    const bf16x8 (&af)[ITILES], bf16x8 b0, bf16x8 b1,
    f32x4 (&rmin)[ITILES], unsigned int* ldscol, int colw, int lane,
    const f32x4& zf)
{
    f32x4 cp0 = {3e38f, 3e38f, 3e38f, 3e38f};
    f32x4 cp1 = {3e38f, 3e38f, 3e38f, 3e38f};
#pragma unroll
    for (int it = 0; it < ITILES; it += 2) {
        f32x4 d00 = __builtin_amdgcn_mfma_f32_16x16x32_bf16(af[it],     b0, zf, 0, 0, 0);
        f32x4 d01 = __builtin_amdgcn_mfma_f32_16x16x32_bf16(af[it],     b1, zf, 0, 0, 0);
        f32x4 d10 = __builtin_amdgcn_mfma_f32_16x16x32_bf16(af[it + 1], b0, zf, 0, 0, 0);
        f32x4 d11 = __builtin_amdgcn_mfma_f32_16x16x32_bf16(af[it + 1], b1, zf, 0, 0, 0);
#pragma unroll
        for (int r = 0; r < 4; ++r) {
            rmin[it][r]     = fminf(fminf(d00[r], d01[r]), rmin[it][r]);     // min3
            rmin[it + 1][r] = fminf(fminf(d10[r], d11[r]), rmin[it + 1][r]); // min3
            cp0[r]          = fminf(fminf(d00[r], d10[r]), cp0[r]);          // min3
            cp1[r]          = fminf(fminf(d01[r], d11[r]), cp1[r]);          // min3
        }
    }
    float c0 = fminf(fminf(cp0[0], cp0[1]), fminf(cp0[2], cp0[3]));
    float c1 = fminf(fminf(cp1[0], cp1[1]), fminf(cp1[2], cp1[3]));
    c0 = fminf(c0, __shfl_xor(c0, 16, 64));
    c0 = fminf(c0, __shfl_xor(c0, 32, 64));
    c1 = fminf(c1, __shfl_xor(c1, 16, 64));
    c1 = fminf(c1, __shfl_xor(c1, 32, 64));
    c0 = fmaxf(c0, 0.f);                 // bit-pattern uint-min == float-min
    c1 = fmaxf(c1, 0.f);
    if (lane < 16) {
        atomicMin(&ldscol[colw + lane],      __float_as_uint(c0));
        atomicMin(&ldscol[colw + 16 + lane], __float_as_uint(c1));
    }
}

// ---------------------------------------------------------------------------
// Fused kernel: encode A (registers) + B (LDS, fragment order) on the fly,
// then MFMA main loop reading B via sequential conflict-free ds_read_b128.
// Partial row/col mins written with plain coalesced stores (no global atomics).
// ---------------------------------------------------------------------------
__global__ __launch_bounds__(256, 4) void chamfer_fused(
    const float* __restrict__ pred, const float* __restrict__ target,
    float* __restrict__ rowpart, float* __restrict__ colpart,
    float* __restrict__ out, const float* __restrict__ bpp,
    const float* __restrict__ lamda)
{
    __shared__ short bB[(JT + 2) * 512];         // 34 KB; +2 tiles prefetch slack
    __shared__ unsigned int ldscol[CHUNK];       // 2 KB
    __shared__ float ldsrow[ROWS_PER_BLOCK];     // 2 KB

    const int tid  = threadIdx.x;
    const int lane = tid & 63;
    const int w    = tid >> 6;
    const int bid  = blockIdx.x;
    const int ck   = bid & (CHUNKS - 1);
    const int rb   = (bid >> 4) & (ROWBLKS - 1);
    const int b    = bid >> 8;

    if (bid == 0 && tid == 0) out[0] = lamda[0] * bpp[0];  // init for atomicAdd

    for (int i = tid; i < CHUNK; i += 256) ldscol[i] = 0x7F7F7F7Fu;

    const int row0 = rb * ROWS_PER_BLOCK + w * ROWS_PER_WAVE;
    const int col0 = ck * CHUNK;
    const float* asrc = pred   + (size_t)b * NPTS * 3;
    const float* bsrc = target + (size_t)b * NPTS * 3;
    const unsigned short ONE = 0x3F80u;

    // ---- B encode into LDS, fragment order: byte (pc>>4)*1024 + h*256 + (pc&15)*16
    //      (reads become tile*1024 + lane*16: sequential; writes 2/bank = free)
    for (int pc = tid; pc < CHUNK; pc += 256) {
        int g = col0 + pc;
        float x = bsrc[3 * g + 0], y = bsrc[3 * g + 1], z = bsrc[3 * g + 2];
        float pp = fmaf(x, x, fmaf(y, y, z * z));
        union { unsigned short e[32]; uint4 q[4]; } u;
#pragma unroll
        for (int i = 0; i < 32; i++) u.e[i] = 0;
        unsigned short H, M, L;
        split3(x, H, M, L);  u.e[0]=H;  u.e[1]=M;  u.e[2]=H;  u.e[3]=L;  u.e[4]=H;  u.e[5]=M;
        split3(y, H, M, L);  u.e[6]=H;  u.e[7]=M;  u.e[8]=H;  u.e[9]=L;  u.e[10]=H; u.e[11]=M;
        split3(z, H, M, L);  u.e[12]=H; u.e[13]=M; u.e[14]=H; u.e[15]=L; u.e[16]=H; u.e[17]=M;
        split3(pp, H, M, L); u.e[18]=ONE; u.e[19]=ONE; u.e[20]=ONE;
                             u.e[21]=H;   u.e[22]=M;   u.e[23]=L;
        char* base = (char*)bB + (pc >> 4) * 1024 + (pc & 15) * 16;
        *(uint4*)(base +   0) = u.q[0];
        *(uint4*)(base + 256) = u.q[1];
        *(uint4*)(base + 512) = u.q[2];
        *(uint4*)(base + 768) = u.q[3];
    }

    // ---- A encode in registers: lane holds rows (it,lane&15), k-quarter lane>>4
    bf16x8 af[ITILES];
    {
        const int r = lane & 15, h = lane >> 4;
#pragma unroll
        for (int it = 0; it < ITILES; ++it) {
            int g = row0 + it * 16 + r;
            float x = asrc[3 * g + 0], y = asrc[3 * g + 1], z = asrc[3 * g + 2];
            float pp = fmaf(x, x, fmaf(y, y, z * z));
            unsigned short xH,xM,xL, yH,yM,yL, zH,zM,zL, pH,pM,pL;
            split3(-2.f * x, xH, xM, xL);
            split3(-2.f * y, yH, yM, yL);
            split3(-2.f * z, zH, zM, zL);
            split3(pp, pH, pM, pL);
            // A slot pattern per coord: [H H M H L M]; pp at 18..20; ONE at 21..23
            bf16x8 q0, q1, q2;
            q0[0]=(short)xH; q0[1]=(short)xH; q0[2]=(short)xM; q0[3]=(short)xH;
            q0[4]=(short)xL; q0[5]=(short)xM; q0[6]=(short)yH; q0[7]=(short)yH;
            q1[0]=(short)yM; q1[1]=(short)yH; q1[2]=(short)yL; q1[3]=(short)yM;
            q1[4]=(short)zH; q1[5]=(short)zH; q1[6]=(short)zM; q1[7]=(short)zH;
            q2[0]=(short)zL; q2[1]=(short)zM; q2[2]=(short)pH; q2[3]=(short)pM;
            q2[4]=(short)pL; q2[5]=(short)ONE; q2[6]=(short)ONE; q2[7]=(short)ONE;
            bf16x8 qz = {0,0,0,0,0,0,0,0};
            bf16x8 s0 = (h & 1) ? q1 : q0;
            bf16x8 s1 = (h & 1) ? qz : q2;
            af[it] = (h & 2) ? s1 : s0;
        }
    }

    f32x4 rmin[ITILES];
#pragma unroll
    for (int it = 0; it < ITILES; ++it) {
        rmin[it][0] = 3e38f; rmin[it][1] = 3e38f;
        rmin[it][2] = 3e38f; rmin[it][3] = 3e38f;
    }
    const f32x4 zf = {0.f, 0.f, 0.f, 0.f};

    __syncthreads();  // B encode + ldscol init visible

    // ---- main loop: sequential ds_read_b128, 1-pair-deep prefetch
    const char* bb = (const char*)bB + lane * 16;
    bf16x8 B0 = *(const bf16x8*)(bb);
    bf16x8 B1 = *(const bf16x8*)(bb + 1024);
    int colw = 0;
#pragma unroll 4
    for (int jt = 0; jt < JT; jt += 2) {
        bf16x8 Bn0 = *(const bf16x8*)(bb + (jt + 2) * 1024);  // last iter: slack
        bf16x8 Bn1 = *(const bf16x8*)(bb + (jt + 3) * 1024);  // tiles, unused
        tile_pair(af, B0, B1, rmin, ldscol, colw, lane, zf);
        colw += 32;
        B0 = Bn0; B1 = Bn1;
    }

    // ---- row-min epilogue: reduce 16 col lanes, stage LDS, coalesced store
#pragma unroll
    for (int it = 0; it < ITILES; ++it) {
#pragma unroll
        for (int r = 0; r < 4; ++r) {
            float v = rmin[it][r];
            v = fminf(v, __shfl_xor(v, 1, 64));
            v = fminf(v, __shfl_xor(v, 2, 64));
            v = fminf(v, __shfl_xor(v, 4, 64));
            v = fminf(v, __shfl_xor(v, 8, 64));
            if ((lane & 15) == 0) {
                int rloc = it * 16 + (lane >> 4) * 4 + r;
                ldsrow[w * ROWS_PER_WAVE + rloc] = fmaxf(v, 0.f);
            }
        }
    }

    __syncthreads();
    // rowpart[b][ck][row], colpart[b][rb][col] — disjoint, plain stores
    for (int i = tid; i < ROWS_PER_BLOCK; i += 256)
        rowpart[((size_t)(b * CHUNKS) + ck) * NPTS + rb * ROWS_PER_BLOCK + i]
            = ldsrow[i];
    for (int i = tid; i < CHUNK; i += 256)
        colpart[((size_t)(b * ROWBLKS) + rb) * NPTS + col0 + i]
            = __uint_as_float(ldscol[i]);
}

// min over 16 slices per row/col cell, block-sum, one atomicAdd per block.
// out was initialized to lamda*bpp by chamfer_fused (stream-ordered).
__global__ __launch_bounds__(256) void reduce_partials(
    const float* __restrict__ rowpart, const float* __restrict__ colpart,
    float* __restrict__ out)
{
    const int tid = threadIdx.x;
    const int gt  = blockIdx.x * 256 + tid;    // 0..16383
    float s = 0.f;
#pragma unroll
    for (int a = 0; a < 2; a++) {
        const float* P = a ? colpart : rowpart;
#pragma unroll
        for (int cc = 0; cc < 2; cc++) {
            int c = gt + cc * 16384;           // 0..32767
            int b = c >> 13, r = c & 8191;
            const float* p = P + (size_t)b * 16 * NPTS + r;
            float m = p[0];
#pragma unroll
            for (int k = 1; k < 16; k++)
                m = fminf(m, p[(size_t)k * NPTS]);
            s += m;
        }
    }
#pragma unroll
    for (int off = 32; off > 0; off >>= 1) s += __shfl_down(s, off, 64);
    __shared__ float red[4];
    int lane = tid & 63, wid = tid >> 6;
    if (lane == 0) red[wid] = s;
    __syncthreads();
    if (tid == 0)
        atomicAdd(out, (red[0] + red[1] + red[2] + red[3]) * (1.0f / 32768.0f));
}

// ---------------------------------------------------------------------------
// Fallback: VALU kernel + atomic partmin (tiny workspace only)
// ---------------------------------------------------------------------------
#define T 256
#define Q 8
#define S 16
#define CH 512
#define NCOMBO 8

__global__ __launch_bounds__(T) void chamfer_partial(
    const float* __restrict__ pred, const float* __restrict__ target,
    unsigned int* __restrict__ partmin)
{
    __shared__ float4 db[CH + 2];

    const int bid   = blockIdx.x;
    const int dbc   = bid & (S - 1);
    const int qc    = (bid >> 4) & 3;
    const int combo = bid >> 6;
    const int dir   = combo & 1;
    const int b     = combo >> 1;

    const float* qptr = (dir == 0 ? pred : target) + (size_t)b * NPTS * 3;
    const float* dptr = (dir == 0 ? target : pred) + (size_t)b * NPTS * 3;

    const int tid = threadIdx.x;

    for (int p = tid; p < CH; p += T) {
        int gj = dbc * CH + p;
        float x = dptr[gj * 3 + 0];
        float y = dptr[gj * 3 + 1];
        float z = dptr[gj * 3 + 2];
        db[p] = make_float4(-2.f * x, -2.f * y, -2.f * z,
                            x * x + y * y + z * z);
    }

    float qx[Q], qy[Q], qz[Q], m[Q];
    int qi0 = qc * (T * Q) + tid;
#pragma unroll
    for (int k = 0; k < Q; k++) {
        int qi = qi0 + k * T;
        qx[k] = qptr[qi * 3 + 0];
        qy[k] = qptr[qi * 3 + 1];
        qz[k] = qptr[qi * 3 + 2];
        m[k]  = 3.4e38f;
    }
    __syncthreads();

    float4 c0 = db[0], c1 = db[1];
    for (int j = 0; j < CH; j += 2) {
        float4 n0 = db[j + 2];
        float4 n1 = db[j + 3];
#pragma unroll
        for (int k = 0; k < Q; k++) {
            float s0 = fmaf(c0.x, qx[k], fmaf(c0.y, qy[k], fmaf(c0.z, qz[k], c0.w)));
            float s1 = fmaf(c1.x, qx[k], fmaf(c1.y, qy[k], fmaf(c1.z, qz[k], c1.w)));
            m[k] = fminf(m[k], fminf(s0, s1));
        }
        c0 = n0; c1 = n1;
    }

#pragma unroll
    for (int k = 0; k < Q; k++) {
        int qi = qi0 + k * T;
        float qq = fmaf(qx[k], qx[k], fmaf(qy[k], qy[k], qz[k] * qz[k]));
        float d2 = fmaxf(m[k] + qq, 0.0f);
        atomicMin(&partmin[combo * NPTS + qi], __float_as_uint(d2));
    }
}

__global__ __launch_bounds__(1024) void reduce_final(
    const unsigned int* __restrict__ partmin,
    const float* __restrict__ bpp, const float* __restrict__ lamda,
    float* __restrict__ out)
{
    const int tid = threadIdx.x;
    float s = 0.f;
#pragma unroll
    for (int k = 0; k < (NCOMBO * NPTS) / 1024; k++)
        s += __uint_as_float(partmin[tid + k * 1024]);

#pragma unroll
    for (int off = 32; off > 0; off >>= 1)
        s += __shfl_down(s, off, 64);

    __shared__ float red[16];
    int lane = tid & 63, wid = tid >> 6;
    if (lane == 0) red[wid] = s;
    __syncthreads();
    if (wid == 0) {
        s = (lane < 16) ? red[lane] : 0.f;
#pragma unroll
        for (int off = 8; off > 0; off >>= 1)
            s += __shfl_down(s, off, 64);
        if (lane == 0)
            out[0] = s * (1.0f / 32768.0f) + lamda[0] * bpp[0];
    }
}

extern "C" void kernel_launch(void* const* d_in, const int* in_sizes, int n_in,
                              void* d_out, int out_size, void* d_ws, size_t ws_size,
                              hipStream_t stream) {
    const float* pred   = (const float*)d_in[0];
    const float* target = (const float*)d_in[1];
    const float* bpp    = (const float*)d_in[2];
    const float* lamda  = (const float*)d_in[3];

    const size_t part_bytes = (size_t)NB * 16 * NPTS * sizeof(float);  // 2 MB

    if (ws_size >= 2 * part_bytes) {
        float* rowpart = (float*)d_ws;
        float* colpart = rowpart + (size_t)NB * 16 * NPTS;
        chamfer_fused<<<NB * ROWBLKS * CHUNKS, 256, 0, stream>>>(
            pred, target, rowpart, colpart, (float*)d_out, bpp, lamda);
        reduce_partials<<<64, 256, 0, stream>>>(rowpart, colpart, (float*)d_out);
    } else {
        unsigned int* partmin = (unsigned int*)d_ws;
        hipMemsetAsync(partmin, 0x7F, (size_t)NCOMBO * NPTS * sizeof(unsigned int),
                       stream);
        chamfer_partial<<<NCOMBO * 4 * S, T, 0, stream>>>(pred, target, partmin);
        reduce_final<<<1, 1024, 0, stream>>>(partmin, bpp, lamda, (float*)d_out);
    }
}

// Round 4
// 113.254 us; speedup vs baseline: 4.4934x; 4.4934x over previous
//
#include <hip/hip_runtime.h>

#define NPTS 8192
#define NB 4

// ---------------- fused-kernel configuration ----------------
#define WPB 4                               // waves per block
#define ITILES 8                            // 16-row MFMA tiles per wave
#define ROWS_PER_WAVE (ITILES * 16)         // 128
#define ROWS_PER_BLOCK (WPB * ROWS_PER_WAVE)// 512
#define CHUNK 512                           // cols per block
#define JT (CHUNK / 16)                     // 32 col tiles
#define CHUNKS (NPTS / CHUNK)               // 16
#define ROWBLKS (NPTS / ROWS_PER_BLOCK)     // 16

using bf16x8 = __attribute__((ext_vector_type(8))) short;
using f32x4  = __attribute__((ext_vector_type(4))) float;

// bf16 round-to-nearest-even, manual
__device__ __forceinline__ unsigned short bfb(float v) {
    unsigned int x = __float_as_uint(v);
    return (unsigned short)((x + 0x7FFFu + ((x >> 16) & 1u)) >> 16);
}
__device__ __forceinline__ float bff(unsigned short u) {
    return __uint_as_float(((unsigned int)u) << 16);
}
// 3-way bf16 split: v ~= H + M + L (captures full fp32 mantissa)
__device__ __forceinline__ void split3(float v, unsigned short& H,
                                       unsigned short& M, unsigned short& L) {
    H = bfb(v); float r = v - bff(H);
    M = bfb(r); L = bfb(r - bff(M));
}

// ---------------------------------------------------------------------------
// 2x2 tile group: 16 MFMAs, min3-paired reductions (~1 VALU op per element).
// All math + layouts HW-verified (rounds 1-3, absmax 0.0).
// ---------------------------------------------------------------------------
__device__ __forceinline__ void tile_pair(
    const bf16x8 (&af)[ITILES], bf16x8 b0, bf16x8 b1,
    f32x4 (&rmin)[ITILES], unsigned int* ldscol, int colw, int lane,
    const f32x4& zf)
{
    f32x4 cp0 = {3e38f, 3e38f, 3e38f, 3e38f};
    f32x4 cp1 = {3e38f, 3e38f, 3e38f, 3e38f};
#pragma unroll
    for (int it = 0; it < ITILES; it += 2) {
        f32x4 d00 = __builtin_amdgcn_mfma_f32_16x16x32_bf16(af[it],     b0, zf, 0, 0, 0);
        f32x4 d01 = __builtin_amdgcn_mfma_f32_16x16x32_bf16(af[it],     b1, zf, 0, 0, 0);
        f32x4 d10 = __builtin_amdgcn_mfma_f32_16x16x32_bf16(af[it + 1], b0, zf, 0, 0, 0);
        f32x4 d11 = __builtin_amdgcn_mfma_f32_16x16x32_bf16(af[it + 1], b1, zf, 0, 0, 0);
#pragma unroll
        for (int r = 0; r < 4; ++r) {
            rmin[it][r]     = fminf(fminf(d00[r], d01[r]), rmin[it][r]);     // min3
            rmin[it + 1][r] = fminf(fminf(d10[r], d11[r]), rmin[it + 1][r]); // min3
            cp0[r]          = fminf(fminf(d00[r], d10[r]), cp0[r]);          // min3
            cp1[r]          = fminf(fminf(d01[r], d11[r]), cp1[r]);          // min3
        }
    }
    float c0 = fminf(fminf(cp0[0], cp0[1]), fminf(cp0[2], cp0[3]));
    float c1 = fminf(fminf(cp1[0], cp1[1]), fminf(cp1[2], cp1[3]));
    c0 = fminf(c0, __shfl_xor(c0, 16, 64));
    c0 = fminf(c0, __shfl_xor(c0, 32, 64));
    c1 = fminf(c1, __shfl_xor(c1, 16, 64));
    c1 = fminf(c1, __shfl_xor(c1, 32, 64));
    c0 = fmaxf(c0, 0.f);                 // bit-pattern uint-min == float-min
    c1 = fmaxf(c1, 0.f);
    if (lane < 16) {
        atomicMin(&ldscol[colw + lane],      __float_as_uint(c0));
        atomicMin(&ldscol[colw + 16 + lane], __float_as_uint(c1));
    }
}

// ---------------------------------------------------------------------------
// Fused kernel. A-encode staged THROUGH LDS (bB reused), not registers:
// round-3's in-register A-encode + unroll-4 spilled af/rmin to scratch
// (1.5 GB HBM traffic, 445 us). This keeps round-2's main-loop register
// shape (64 VGPR, no spill) while staying a single kernel.
// ---------------------------------------------------------------------------
__global__ __launch_bounds__(256, 4) void chamfer_fused(
    const float* __restrict__ pred, const float* __restrict__ target,
    float* __restrict__ rowpart, float* __restrict__ colpart,
    float* __restrict__ out, const float* __restrict__ bpp,
    const float* __restrict__ lamda)
{
    __shared__ short bB[(JT + 2) * 512];         // 34816 B; A-stage fits (32 KB)
    __shared__ unsigned int ldscol[CHUNK];       // 2 KB
    __shared__ float ldsrow[ROWS_PER_BLOCK];     // 2 KB

    const int tid  = threadIdx.x;
    const int lane = tid & 63;
    const int w    = tid >> 6;
    const int bid  = blockIdx.x;
    const int ck   = bid & (CHUNKS - 1);
    const int rb   = (bid >> 4) & (ROWBLKS - 1);
    const int b    = bid >> 8;

    if (bid == 0 && tid == 0) out[0] = lamda[0] * bpp[0];  // init for atomicAdd

    for (int i = tid; i < CHUNK; i += 256) ldscol[i] = 0x7F7F7F7Fu;

    const int col0 = ck * CHUNK;
    const float* asrc = pred   + (size_t)b * NPTS * 3;
    const float* bsrc = target + (size_t)b * NPTS * 3;
    const unsigned short ONE = 0x3F80u;

    // ---- Phase 1: A-encode into LDS, fragment order, per-wave 8 KB region.
    //      Row i of block: wave i>>7, tile (i&127)>>4, row-in-tile i&15.
    //      A slot pattern per coord: [H H M H L M]; pp at 18..20; ONE at 21..23.
    for (int i = tid; i < ROWS_PER_BLOCK; i += 256) {
        int g = rb * ROWS_PER_BLOCK + i;
        float x = asrc[3 * g + 0], y = asrc[3 * g + 1], z = asrc[3 * g + 2];
        float pp = fmaf(x, x, fmaf(y, y, z * z));
        union { unsigned short e[32]; uint4 q[4]; } u;
#pragma unroll
        for (int j = 0; j < 32; j++) u.e[j] = 0;
        unsigned short H, M, L;
        split3(-2.f * x, H, M, L); u.e[0]=H;  u.e[1]=H;  u.e[2]=M;  u.e[3]=H;  u.e[4]=L;  u.e[5]=M;
        split3(-2.f * y, H, M, L); u.e[6]=H;  u.e[7]=H;  u.e[8]=M;  u.e[9]=H;  u.e[10]=L; u.e[11]=M;
        split3(-2.f * z, H, M, L); u.e[12]=H; u.e[13]=H; u.e[14]=M; u.e[15]=H; u.e[16]=L; u.e[17]=M;
        split3(pp, H, M, L);       u.e[18]=H; u.e[19]=M; u.e[20]=L;
                                   u.e[21]=ONE; u.e[22]=ONE; u.e[23]=ONE;
        char* base = (char*)bB + (i >> 7) * 8192 + ((i & 127) >> 4) * 1024 + (i & 15) * 16;
        *(uint4*)(base +   0) = u.q[0];
        *(uint4*)(base + 256) = u.q[1];
        *(uint4*)(base + 512) = u.q[2];
        *(uint4*)(base + 768) = u.q[3];
    }
    __syncthreads();

    // ---- Phase 2: lanes pull A-fragments (sequential ds_read_b128)
    bf16x8 af[ITILES];
    {
        const char* ab = (const char*)bB + w * 8192 + lane * 16;
#pragma unroll
        for (int it = 0; it < ITILES; ++it)
            af[it] = *(const bf16x8*)(ab + it * 1024);
    }
    __syncthreads();   // drains lgkm: A reads done before B overwrites

    // ---- Phase 3: B-encode into LDS, fragment order (overwrites bB).
    //      B slot pattern per coord: [H M H L H M]; ONE at 18..20; pp at 21..23.
    for (int pc = tid; pc < CHUNK; pc += 256) {
        int g = col0 + pc;
        float x = bsrc[3 * g + 0], y = bsrc[3 * g + 1], z = bsrc[3 * g + 2];
        float pp = fmaf(x, x, fmaf(y, y, z * z));
        union { unsigned short e[32]; uint4 q[4]; } u;
#pragma unroll
        for (int i = 0; i < 32; i++) u.e[i] = 0;
        unsigned short H, M, L;
        split3(x, H, M, L);  u.e[0]=H;  u.e[1]=M;  u.e[2]=H;  u.e[3]=L;  u.e[4]=H;  u.e[5]=M;
        split3(y, H, M, L);  u.e[6]=H;  u.e[7]=M;  u.e[8]=H;  u.e[9]=L;  u.e[10]=H; u.e[11]=M;
        split3(z, H, M, L);  u.e[12]=H; u.e[13]=M; u.e[14]=H; u.e[15]=L; u.e[16]=H; u.e[17]=M;
        split3(pp, H, M, L); u.e[18]=ONE; u.e[19]=ONE; u.e[20]=ONE;
                             u.e[21]=H;   u.e[22]=M;   u.e[23]=L;
        char* base = (char*)bB + (pc >> 4) * 1024 + (pc & 15) * 16;
        *(uint4*)(base +   0) = u.q[0];
        *(uint4*)(base + 256) = u.q[1];
        *(uint4*)(base + 512) = u.q[2];
        *(uint4*)(base + 768) = u.q[3];
    }

    f32x4 rmin[ITILES];
#pragma unroll
    for (int it = 0; it < ITILES; ++it) {
        rmin[it][0] = 3e38f; rmin[it][1] = 3e38f;
        rmin[it][2] = 3e38f; rmin[it][3] = 3e38f;
    }
    const f32x4 zf = {0.f, 0.f, 0.f, 0.f};

    __syncthreads();  // B encode + ldscol init visible

    // ---- Phase 4: main loop, sequential ds_read_b128, 1-pair-deep prefetch
    const char* bb = (const char*)bB + lane * 16;
    bf16x8 B0 = *(const bf16x8*)(bb);
    bf16x8 B1 = *(const bf16x8*)(bb + 1024);
    int colw = 0;
    for (int jt = 0; jt < JT; jt += 2) {
        bf16x8 Bn0 = *(const bf16x8*)(bb + (jt + 2) * 1024);  // last iter: slack
        bf16x8 Bn1 = *(const bf16x8*)(bb + (jt + 3) * 1024);  // tiles, unused
        tile_pair(af, B0, B1, rmin, ldscol, colw, lane, zf);
        colw += 32;
        B0 = Bn0; B1 = Bn1;
    }

    // ---- row-min epilogue: reduce 16 col lanes, stage LDS, coalesced store
#pragma unroll
    for (int it = 0; it < ITILES; ++it) {
#pragma unroll
        for (int r = 0; r < 4; ++r) {
            float v = rmin[it][r];
            v = fminf(v, __shfl_xor(v, 1, 64));
            v = fminf(v, __shfl_xor(v, 2, 64));
            v = fminf(v, __shfl_xor(v, 4, 64));
            v = fminf(v, __shfl_xor(v, 8, 64));
            if ((lane & 15) == 0) {
                int rloc = it * 16 + (lane >> 4) * 4 + r;
                ldsrow[w * ROWS_PER_WAVE + rloc] = fmaxf(v, 0.f);
            }
        }
    }

    __syncthreads();
    // rowpart[b][ck][row], colpart[b][rb][col] — disjoint, plain stores
    for (int i = tid; i < ROWS_PER_BLOCK; i += 256)
        rowpart[((size_t)(b * CHUNKS) + ck) * NPTS + rb * ROWS_PER_BLOCK + i]
            = ldsrow[i];
    for (int i = tid; i < CHUNK; i += 256)
        colpart[((size_t)(b * ROWBLKS) + rb) * NPTS + col0 + i]
            = __uint_as_float(ldscol[i]);
}

// min over 16 slices per row/col cell, block-sum, one atomicAdd per block.
// out was initialized to lamda*bpp by chamfer_fused (stream-ordered).
__global__ __launch_bounds__(256) void reduce_partials(
    const float* __restrict__ rowpart, const float* __restrict__ colpart,
    float* __restrict__ out)
{
    const int tid = threadIdx.x;
    const int gt  = blockIdx.x * 256 + tid;    // 0..16383
    float s = 0.f;
#pragma unroll
    for (int a = 0; a < 2; a++) {
        const float* P = a ? colpart : rowpart;
#pragma unroll
        for (int cc = 0; cc < 2; cc++) {
            int c = gt + cc * 16384;           // 0..32767
            int b = c >> 13, r = c & 8191;
            const float* p = P + (size_t)b * 16 * NPTS + r;
            float m = p[0];
#pragma unroll
            for (int k = 1; k < 16; k++)
                m = fminf(m, p[(size_t)k * NPTS]);
            s += m;
        }
    }
#pragma unroll
    for (int off = 32; off > 0; off >>= 1) s += __shfl_down(s, off, 64);
    __shared__ float red[4];
    int lane = tid & 63, wid = tid >> 6;
    if (lane == 0) red[wid] = s;
    __syncthreads();
    if (tid == 0)
        atomicAdd(out, (red[0] + red[1] + red[2] + red[3]) * (1.0f / 32768.0f));
}

// ---------------------------------------------------------------------------
// Fallback: VALU kernel + atomic partmin (tiny workspace only)
// ---------------------------------------------------------------------------
#define T 256
#define Q 8
#define S 16
#define CH 512
#define NCOMBO 8

__global__ __launch_bounds__(T) void chamfer_partial(
    const float* __restrict__ pred, const float* __restrict__ target,
    unsigned int* __restrict__ partmin)
{
    __shared__ float4 db[CH + 2];

    const int bid   = blockIdx.x;
    const int dbc   = bid & (S - 1);
    const int qc    = (bid >> 4) & 3;
    const int combo = bid >> 6;
    const int dir   = combo & 1;
    const int b     = combo >> 1;

    const float* qptr = (dir == 0 ? pred : target) + (size_t)b * NPTS * 3;
    const float* dptr = (dir == 0 ? target : pred) + (size_t)b * NPTS * 3;

    const int tid = threadIdx.x;

    for (int p = tid; p < CH; p += T) {
        int gj = dbc * CH + p;
        float x = dptr[gj * 3 + 0];
        float y = dptr[gj * 3 + 1];
        float z = dptr[gj * 3 + 2];
        db[p] = make_float4(-2.f * x, -2.f * y, -2.f * z,
                            x * x + y * y + z * z);
    }

    float qx[Q], qy[Q], qz[Q], m[Q];
    int qi0 = qc * (T * Q) + tid;
#pragma unroll
    for (int k = 0; k < Q; k++) {
        int qi = qi0 + k * T;
        qx[k] = qptr[qi * 3 + 0];
        qy[k] = qptr[qi * 3 + 1];
        qz[k] = qptr[qi * 3 + 2];
        m[k]  = 3.4e38f;
    }
    __syncthreads();

    float4 c0 = db[0], c1 = db[1];
    for (int j = 0; j < CH; j += 2) {
        float4 n0 = db[j + 2];
        float4 n1 = db[j + 3];
#pragma unroll
        for (int k = 0; k < Q; k++) {
            float s0 = fmaf(c0.x, qx[k], fmaf(c0.y, qy[k], fmaf(c0.z, qz[k], c0.w)));
            float s1 = fmaf(c1.x, qx[k], fmaf(c1.y, qy[k], fmaf(c1.z, qz[k], c1.w)));
            m[k] = fminf(m[k], fminf(s0, s1));
        }
        c0 = n0; c1 = n1;
    }

#pragma unroll
    for (int k = 0; k < Q; k++) {
        int qi = qi0 + k * T;
        float qq = fmaf(qx[k], qx[k], fmaf(qy[k], qy[k], qz[k] * qz[k]));
        float d2 = fmaxf(m[k] + qq, 0.0f);
        atomicMin(&partmin[combo * NPTS + qi], __float_as_uint(d2));
    }
}

__global__ __launch_bounds__(1024) void reduce_final(
    const unsigned int* __restrict__ partmin,
    const float* __restrict__ bpp, const float* __restrict__ lamda,
    float* __restrict__ out)
{
    const int tid = threadIdx.x;
    float s = 0.f;
#pragma unroll
    for (int k = 0; k < (NCOMBO * NPTS) / 1024; k++)
        s += __uint_as_float(partmin[tid + k * 1024]);

#pragma unroll
    for (int off = 32; off > 0; off >>= 1)
        s += __shfl_down(s, off, 64);

    __shared__ float red[16];
    int lane = tid & 63, wid = tid >> 6;
    if (lane == 0) red[wid] = s;
    __syncthreads();
    if (wid == 0) {
        s = (lane < 16) ? red[lane] : 0.f;
#pragma unroll
        for (int off = 8; off > 0; off >>= 1)
            s += __shfl_down(s, off, 64);
        if (lane == 0)
            out[0] = s * (1.0f / 32768.0f) + lamda[0] * bpp[0];
    }
}

extern "C" void kernel_launch(void* const* d_in, const int* in_sizes, int n_in,
                              void* d_out, int out_size, void* d_ws, size_t ws_size,
                              hipStream_t stream) {
    const float* pred   = (const float*)d_in[0];
    const float* target = (const float*)d_in[1];
    const float* bpp    = (const float*)d_in[2];
    const float* lamda  = (const float*)d_in[3];

    const size_t part_bytes = (size_t)NB * 16 * NPTS * sizeof(float);  // 2 MB

    if (ws_size >= 2 * part_bytes) {
        float* rowpart = (float*)d_ws;
        float* colpart = rowpart + (size_t)NB * 16 * NPTS;
        chamfer_fused<<<NB * ROWBLKS * CHUNKS, 256, 0, stream>>>(
            pred, target, rowpart, colpart, (float*)d_out, bpp, lamda);
        reduce_partials<<<64, 256, 0, stream>>>(rowpart, colpart, (float*)d_out);
    } else {
        unsigned int* partmin = (unsigned int*)d_ws;
        hipMemsetAsync(partmin, 0x7F, (size_t)NCOMBO * NPTS * sizeof(unsigned int),
                       stream);
        chamfer_partial<<<NCOMBO * 4 * S, T, 0, stream>>>(pred, target, partmin);
        reduce_final<<<1, 1024, 0, stream>>>(partmin, bpp, lamda, (float*)d_out);
    }
}

// Round 5
// 85.267 us; speedup vs baseline: 5.9683x; 1.3282x over previous
//
#include <hip/hip_runtime.h>

#define NPTS 8192
#define NB 4

// ---------------- fused-kernel configuration ----------------
#define WPB 4                               // waves per block
#define ITILES 8                            // 16-row MFMA tiles per wave
#define ROWS_PER_WAVE (ITILES * 16)         // 128
#define ROWS_PER_BLOCK (WPB * ROWS_PER_WAVE)// 512
#define CHUNK 512                           // cols per block
#define JT (CHUNK / 16)                     // 32 col tiles
#define CHUNKS (NPTS / CHUNK)               // 16
#define ROWBLKS (NPTS / ROWS_PER_BLOCK)     // 16

using bf16x8 = __attribute__((ext_vector_type(8))) short;
using f32x4  = __attribute__((ext_vector_type(4))) float;

// bf16 round-to-nearest-even, manual
__device__ __forceinline__ unsigned short bfb(float v) {
    unsigned int x = __float_as_uint(v);
    return (unsigned short)((x + 0x7FFFu + ((x >> 16) & 1u)) >> 16);
}
__device__ __forceinline__ float bff(unsigned short u) {
    return __uint_as_float(((unsigned int)u) << 16);
}
// 3-way bf16 split: v ~= H + M + L (captures full fp32 mantissa)
__device__ __forceinline__ void split3(float v, unsigned short& H,
                                       unsigned short& M, unsigned short& L) {
    H = bfb(v); float r = v - bff(H);
    M = bfb(r); L = bfb(r - bff(M));
}
__device__ __forceinline__ unsigned int pk(unsigned short lo, unsigned short hi) {
    return (unsigned int)lo | ((unsigned int)hi << 16);
}
__device__ __forceinline__ unsigned int umn(unsigned int a, unsigned int b) {
    return a < b ? a : b;
}

// ---------------------------------------------------------------------------
// 2x2 tile group: 16 MFMAs, min3-paired reductions (~1 VALU op per element).
// Col partial: collapse cp[4] -> scalar, full-wave LDS atomicMin into
// colh[hi][col] (64 distinct addrs, no shfl, no divergence). Cross-hi merge
// deferred to epilogue. Encode math + layouts HW-verified (rounds 1-4).
// ---------------------------------------------------------------------------
__device__ __forceinline__ void tile_pair(
    const bf16x8 (&af)[ITILES], bf16x8 b0, bf16x8 b1,
    f32x4 (&rmin)[ITILES], unsigned int* colh, int colw, int lane,
    const f32x4& zf)
{
    f32x4 cp0 = {3e38f, 3e38f, 3e38f, 3e38f};
    f32x4 cp1 = {3e38f, 3e38f, 3e38f, 3e38f};
#pragma unroll
    for (int it = 0; it < ITILES; it += 2) {
        f32x4 d00 = __builtin_amdgcn_mfma_f32_16x16x32_bf16(af[it],     b0, zf, 0, 0, 0);
        f32x4 d01 = __builtin_amdgcn_mfma_f32_16x16x32_bf16(af[it],     b1, zf, 0, 0, 0);
        f32x4 d10 = __builtin_amdgcn_mfma_f32_16x16x32_bf16(af[it + 1], b0, zf, 0, 0, 0);
        f32x4 d11 = __builtin_amdgcn_mfma_f32_16x16x32_bf16(af[it + 1], b1, zf, 0, 0, 0);
#pragma unroll
        for (int r = 0; r < 4; ++r) {
            rmin[it][r]     = fminf(fminf(d00[r], d01[r]), rmin[it][r]);     // min3
            rmin[it + 1][r] = fminf(fminf(d10[r], d11[r]), rmin[it + 1][r]); // min3
            cp0[r]          = fminf(fminf(d00[r], d10[r]), cp0[r]);          // min3
            cp1[r]          = fminf(fminf(d01[r], d11[r]), cp1[r]);          // min3
        }
    }
    float c0 = fminf(fminf(cp0[0], cp0[1]), fminf(cp0[2], cp0[3]));
    float c1 = fminf(fminf(cp1[0], cp1[1]), fminf(cp1[2], cp1[3]));
    c0 = fmaxf(c0, 0.f);                 // bit-pattern uint-min == float-min
    c1 = fmaxf(c1, 0.f);
    const int a = (lane >> 4) * CHUNK + colw + (lane & 15);
    atomicMin(&colh[a],      __float_as_uint(c0));
    atomicMin(&colh[a + 16], __float_as_uint(c1));
}

// ---------------------------------------------------------------------------
// Fused kernel. Encode quarters built directly as uint4 (32-bit packing) —
// round-4's short[32]/uint4 union forced scratch (WRITE_SIZE 29.7 MB vs
// 4.2 MB designed). LDS = bB 32 KB + colh 8 KB = 40960 B -> 4 blocks/CU.
// ---------------------------------------------------------------------------
__global__ __launch_bounds__(256, 4) void chamfer_fused(
    const float* __restrict__ pred, const float* __restrict__ target,
    float* __restrict__ rowpart, float* __restrict__ colpart,
    float* __restrict__ out, const float* __restrict__ bpp,
    const float* __restrict__ lamda)
{
    __shared__ short bB[JT * 512];               // 32768 B (A-stage reuses it)
    __shared__ unsigned int colh[4 * CHUNK];     // 8192 B: [hi][col]

    const int tid  = threadIdx.x;
    const int lane = tid & 63;
    const int w    = tid >> 6;
    const int bid  = blockIdx.x;
    const int ck   = bid & (CHUNKS - 1);
    const int rb   = (bid >> 4) & (ROWBLKS - 1);
    const int b    = bid >> 8;

    if (bid == 0 && tid == 0) out[0] = lamda[0] * bpp[0];  // init for atomicAdd

    for (int i = tid; i < 4 * CHUNK; i += 256) colh[i] = 0x7F7F7F7Fu;

    const int col0 = ck * CHUNK;
    const float* asrc = pred   + (size_t)b * NPTS * 3;
    const float* bsrc = target + (size_t)b * NPTS * 3;
    const unsigned short ONE = 0x3F80u;

    // ---- Phase 1: A-encode into LDS, fragment order, per-wave 8 KB region.
    //      A slot pattern per coord: [H H M H L M]; pp at 18..20; ONE 21..23;
    //      quarter 3 = zeros (covers K slots 24..31 for BOTH operands).
    for (int i = tid; i < ROWS_PER_BLOCK; i += 256) {
        int g = rb * ROWS_PER_BLOCK + i;
        float x = asrc[3 * g + 0], y = asrc[3 * g + 1], z = asrc[3 * g + 2];
        float pp = fmaf(x, x, fmaf(y, y, z * z));
        unsigned short xH,xM,xL, yH,yM,yL, zH,zM,zL, pH,pM,pL;
        split3(-2.f * x, xH, xM, xL);
        split3(-2.f * y, yH, yM, yL);
        split3(-2.f * z, zH, zM, zL);
        split3(pp, pH, pM, pL);
        uint4 q0 = make_uint4(pk(xH,xH), pk(xM,xH), pk(xL,xM), pk(yH,yH));
        uint4 q1 = make_uint4(pk(yM,yH), pk(yL,yM), pk(zH,zH), pk(zM,zH));
        uint4 q2 = make_uint4(pk(zL,zM), pk(pH,pM), pk(pL,ONE), pk(ONE,ONE));
        uint4 q3 = make_uint4(0u, 0u, 0u, 0u);
        char* base = (char*)bB + (i >> 7) * 8192 + ((i & 127) >> 4) * 1024 + (i & 15) * 16;
        *(uint4*)(base +   0) = q0;
        *(uint4*)(base + 256) = q1;
        *(uint4*)(base + 512) = q2;
        *(uint4*)(base + 768) = q3;
    }
    __syncthreads();

    // ---- Phase 2: lanes pull A-fragments (sequential ds_read_b128)
    bf16x8 af[ITILES];
    {
        const char* ab = (const char*)bB + w * 8192 + lane * 16;
#pragma unroll
        for (int it = 0; it < ITILES; ++it)
            af[it] = *(const bf16x8*)(ab + it * 1024);
    }
    __syncthreads();   // A reads drained before B overwrites

    // ---- Phase 3: B-encode (overwrites bB). Slot pattern [H M H L H M];
    //      ONE at 18..20; pp at 21..23. Quarter 3 skipped (A side is zero).
    for (int pc = tid; pc < CHUNK; pc += 256) {
        int g = col0 + pc;
        float x = bsrc[3 * g + 0], y = bsrc[3 * g + 1], z = bsrc[3 * g + 2];
        float pp = fmaf(x, x, fmaf(y, y, z * z));
        unsigned short xH,xM,xL, yH,yM,yL, zH,zM,zL, pH,pM,pL;
        split3(x, xH, xM, xL);
        split3(y, yH, yM, yL);
        split3(z, zH, zM, zL);
        split3(pp, pH, pM, pL);
        uint4 q0 = make_uint4(pk(xH,xM), pk(xH,xL), pk(xH,xM), pk(yH,yM));
        uint4 q1 = make_uint4(pk(yH,yL), pk(yH,yM), pk(zH,zM), pk(zH,zL));
        uint4 q2 = make_uint4(pk(zH,zM), pk(ONE,ONE), pk(ONE,pH), pk(pM,pL));
        char* base = (char*)bB + (pc >> 4) * 1024 + (pc & 15) * 16;
        *(uint4*)(base +   0) = q0;
        *(uint4*)(base + 256) = q1;
        *(uint4*)(base + 512) = q2;
    }

    f32x4 rmin[ITILES];
#pragma unroll
    for (int it = 0; it < ITILES; ++it) {
        rmin[it][0] = 3e38f; rmin[it][1] = 3e38f;
        rmin[it][2] = 3e38f; rmin[it][3] = 3e38f;
    }
    const f32x4 zf = {0.f, 0.f, 0.f, 0.f};

    __syncthreads();  // B encode + colh init visible

    // ---- Phase 4: main loop, sequential ds_read_b128, wrap-clamped prefetch
    const char* bb = (const char*)bB + lane * 16;
    bf16x8 B0 = *(const bf16x8*)(bb);
    bf16x8 B1 = *(const bf16x8*)(bb + 1024);
    int colw = 0;
    for (int jt = 0; jt < JT; jt += 2) {
        int nj = (jt + 2) & (JT - 1);                        // last iter wraps:
        bf16x8 Bn0 = *(const bf16x8*)(bb + nj * 1024);       // valid addr,
        bf16x8 Bn1 = *(const bf16x8*)(bb + (nj + 1) * 1024); // value unused
        tile_pair(af, B0, B1, rmin, colh, colw, lane, zf);
        colw += 32;
        B0 = Bn0; B1 = Bn1;
    }

    // ---- row-min epilogue: shfl-reduce 16 col lanes, direct global store
#pragma unroll
    for (int it = 0; it < ITILES; ++it) {
#pragma unroll
        for (int r = 0; r < 4; ++r) {
            float v = rmin[it][r];
            v = fminf(v, __shfl_xor(v, 1, 64));
            v = fminf(v, __shfl_xor(v, 2, 64));
            v = fminf(v, __shfl_xor(v, 4, 64));
            v = fminf(v, __shfl_xor(v, 8, 64));
            if ((lane & 15) == 0) {
                int row = rb * ROWS_PER_BLOCK + w * ROWS_PER_WAVE
                        + it * 16 + (lane >> 4) * 4 + r;
                rowpart[((size_t)(b * CHUNKS) + ck) * NPTS + row] = fmaxf(v, 0.f);
            }
        }
    }

    // ---- col epilogue: merge 4 hi-groups, coalesced store
    __syncthreads();
    for (int i = tid; i < CHUNK; i += 256) {
        unsigned int m = umn(umn(colh[i],            colh[CHUNK + i]),
                             umn(colh[2 * CHUNK + i], colh[3 * CHUNK + i]));
        colpart[((size_t)(b * ROWBLKS) + rb) * NPTS + col0 + i] = __uint_as_float(m);
    }
}

// min over 16 slices per row/col cell, block-sum, one atomicAdd per block.
// out was initialized to lamda*bpp by chamfer_fused (stream-ordered).
__global__ __launch_bounds__(256) void reduce_partials(
    const float* __restrict__ rowpart, const float* __restrict__ colpart,
    float* __restrict__ out)
{
    const int tid = threadIdx.x;
    const int gt  = blockIdx.x * 256 + tid;    // 0..16383
    float s = 0.f;
#pragma unroll
    for (int a = 0; a < 2; a++) {
        const float* P = a ? colpart : rowpart;
#pragma unroll
        for (int cc = 0; cc < 2; cc++) {
            int c = gt + cc * 16384;           // 0..32767
            int b = c >> 13, r = c & 8191;
            const float* p = P + (size_t)b * 16 * NPTS + r;
            float m = p[0];
#pragma unroll
            for (int k = 1; k < 16; k++)
                m = fminf(m, p[(size_t)k * NPTS]);
            s += m;
        }
    }
#pragma unroll
    for (int off = 32; off > 0; off >>= 1) s += __shfl_down(s, off, 64);
    __shared__ float red[4];
    int lane = tid & 63, wid = tid >> 6;
    if (lane == 0) red[wid] = s;
    __syncthreads();
    if (tid == 0)
        atomicAdd(out, (red[0] + red[1] + red[2] + red[3]) * (1.0f / 32768.0f));
}

// ---------------------------------------------------------------------------
// Fallback: VALU kernel + atomic partmin (tiny workspace only)
// ---------------------------------------------------------------------------
#define T 256
#define Q 8
#define S 16
#define CH 512
#define NCOMBO 8

__global__ __launch_bounds__(T) void chamfer_partial(
    const float* __restrict__ pred, const float* __restrict__ target,
    unsigned int* __restrict__ partmin)
{
    __shared__ float4 db[CH + 2];

    const int bid   = blockIdx.x;
    const int dbc   = bid & (S - 1);
    const int qc    = (bid >> 4) & 3;
    const int combo = bid >> 6;
    const int dir   = combo & 1;
    const int b     = combo >> 1;

    const float* qptr = (dir == 0 ? pred : target) + (size_t)b * NPTS * 3;
    const float* dptr = (dir == 0 ? target : pred) + (size_t)b * NPTS * 3;

    const int tid = threadIdx.x;

    for (int p = tid; p < CH; p += T) {
        int gj = dbc * CH + p;
        float x = dptr[gj * 3 + 0];
        float y = dptr[gj * 3 + 1];
        float z = dptr[gj * 3 + 2];
        db[p] = make_float4(-2.f * x, -2.f * y, -2.f * z,
                            x * x + y * y + z * z);
    }

    float qx[Q], qy[Q], qz[Q], m[Q];
    int qi0 = qc * (T * Q) + tid;
#pragma unroll
    for (int k = 0; k < Q; k++) {
        int qi = qi0 + k * T;
        qx[k] = qptr[qi * 3 + 0];
        qy[k] = qptr[qi * 3 + 1];
        qz[k] = qptr[qi * 3 + 2];
        m[k]  = 3.4e38f;
    }
    __syncthreads();

    float4 c0 = db[0], c1 = db[1];
    for (int j = 0; j < CH; j += 2) {
        float4 n0 = db[j + 2];
        float4 n1 = db[j + 3];
#pragma unroll
        for (int k = 0; k < Q; k++) {
            float s0 = fmaf(c0.x, qx[k], fmaf(c0.y, qy[k], fmaf(c0.z, qz[k], c0.w)));
            float s1 = fmaf(c1.x, qx[k], fmaf(c1.y, qy[k], fmaf(c1.z, qz[k], c1.w)));
            m[k] = fminf(m[k], fminf(s0, s1));
        }
        c0 = n0; c1 = n1;
    }

#pragma unroll
    for (int k = 0; k < Q; k++) {
        int qi = qi0 + k * T;
        float qq = fmaf(qx[k], qx[k], fmaf(qy[k], qy[k], qz[k] * qz[k]));
        float d2 = fmaxf(m[k] + qq, 0.0f);
        atomicMin(&partmin[combo * NPTS + qi], __float_as_uint(d2));
    }
}

__global__ __launch_bounds__(1024) void reduce_final(
    const unsigned int* __restrict__ partmin,
    const float* __restrict__ bpp, const float* __restrict__ lamda,
    float* __restrict__ out)
{
    const int tid = threadIdx.x;
    float s = 0.f;
#pragma unroll
    for (int k = 0; k < (NCOMBO * NPTS) / 1024; k++)
        s += __uint_as_float(partmin[tid + k * 1024]);

#pragma unroll
    for (int off = 32; off > 0; off >>= 1)
        s += __shfl_down(s, off, 64);

    __shared__ float red[16];
    int lane = tid & 63, wid = tid >> 6;
    if (lane == 0) red[wid] = s;
    __syncthreads();
    if (wid == 0) {
        s = (lane < 16) ? red[lane] : 0.f;
#pragma unroll
        for (int off = 8; off > 0; off >>= 1)
            s += __shfl_down(s, off, 64);
        if (lane == 0)
            out[0] = s * (1.0f / 32768.0f) + lamda[0] * bpp[0];
    }
}

extern "C" void kernel_launch(void* const* d_in, const int* in_sizes, int n_in,
                              void* d_out, int out_size, void* d_ws, size_t ws_size,
                              hipStream_t stream) {
    const float* pred   = (const float*)d_in[0];
    const float* target = (const float*)d_in[1];
    const float* bpp    = (const float*)d_in[2];
    const float* lamda  = (const float*)d_in[3];

    const size_t part_bytes = (size_t)NB * 16 * NPTS * sizeof(float);  // 2 MB

    if (ws_size >= 2 * part_bytes) {
        float* rowpart = (float*)d_ws;
        float* colpart = rowpart + (size_t)NB * 16 * NPTS;
        chamfer_fused<<<NB * ROWBLKS * CHUNKS, 256, 0, stream>>>(
            pred, target, rowpart, colpart, (float*)d_out, bpp, lamda);
        reduce_partials<<<64, 256, 0, stream>>>(rowpart, colpart, (float*)d_out);
    } else {
        unsigned int* partmin = (unsigned int*)d_ws;
        hipMemsetAsync(partmin, 0x7F, (size_t)NCOMBO * NPTS * sizeof(unsigned int),
                       stream);
        chamfer_partial<<<NCOMBO * 4 * S, T, 0, stream>>>(pred, target, partmin);
        reduce_final<<<1, 1024, 0, stream>>>(partmin, bpp, lamda, (float*)d_out);
    }
}

// Round 6
// 85.065 us; speedup vs baseline: 5.9825x; 1.0024x over previous
//
#include <hip/hip_runtime.h>

#define NPTS 8192
#define NB 4

// ---------------- fused-kernel configuration ----------------
#define WPB 4                               // waves per block
#define ITILES 8                            // 16-row MFMA tiles per wave
#define ROWS_PER_WAVE (ITILES * 16)         // 128
#define ROWS_PER_BLOCK (WPB * ROWS_PER_WAVE)// 512
#define CHUNK 512                           // cols per block
#define JT (CHUNK / 16)                     // 32 col tiles
#define CHUNKS (NPTS / CHUNK)               // 16
#define ROWBLKS (NPTS / ROWS_PER_BLOCK)     // 16

using bf16x8 = __attribute__((ext_vector_type(8))) short;
using f32x4  = __attribute__((ext_vector_type(4))) float;

// bf16 round-to-nearest-even, manual
__device__ __forceinline__ unsigned short bfb(float v) {
    unsigned int x = __float_as_uint(v);
    return (unsigned short)((x + 0x7FFFu + ((x >> 16) & 1u)) >> 16);
}
__device__ __forceinline__ float bff(unsigned short u) {
    return __uint_as_float(((unsigned int)u) << 16);
}
// 3-way bf16 split: v ~= H + M + L (captures full fp32 mantissa)
__device__ __forceinline__ void split3(float v, unsigned short& H,
                                       unsigned short& M, unsigned short& L) {
    H = bfb(v); float r = v - bff(H);
    M = bfb(r); L = bfb(r - bff(M));
}
__device__ __forceinline__ unsigned int pk(unsigned short lo, unsigned short hi) {
    return (unsigned int)lo | ((unsigned int)hi << 16);
}
__device__ __forceinline__ unsigned int umn(unsigned int a, unsigned int b) {
    return a < b ? a : b;
}

// A-side encode: slot pattern per coord [H H M H L M]; pp 18..20; ONE 21..23;
// quarter 3 zeros (covers K 24..31 for both operands).
__device__ __forceinline__ void encA(float x, float y, float z, char* base) {
    const unsigned short ONE = 0x3F80u;
    float pp = fmaf(x, x, fmaf(y, y, z * z));
    unsigned short xH,xM,xL, yH,yM,yL, zH,zM,zL, pH,pM,pL;
    split3(-2.f * x, xH, xM, xL);
    split3(-2.f * y, yH, yM, yL);
    split3(-2.f * z, zH, zM, zL);
    split3(pp, pH, pM, pL);
    uint4 q0 = make_uint4(pk(xH,xH), pk(xM,xH), pk(xL,xM), pk(yH,yH));
    uint4 q1 = make_uint4(pk(yM,yH), pk(yL,yM), pk(zH,zH), pk(zM,zH));
    uint4 q2 = make_uint4(pk(zL,zM), pk(pH,pM), pk(pL,ONE), pk(ONE,ONE));
    uint4 q3 = make_uint4(0u, 0u, 0u, 0u);
    *(uint4*)(base +   0) = q0;
    *(uint4*)(base + 256) = q1;
    *(uint4*)(base + 512) = q2;
    *(uint4*)(base + 768) = q3;
}
// B-side encode: slot pattern per coord [H M H L H M]; ONE 18..20; pp 21..23.
// Quarter 3 skipped (A side is zero there).
__device__ __forceinline__ void encB(float x, float y, float z, char* base) {
    const unsigned short ONE = 0x3F80u;
    float pp = fmaf(x, x, fmaf(y, y, z * z));
    unsigned short xH,xM,xL, yH,yM,yL, zH,zM,zL, pH,pM,pL;
    split3(x, xH, xM, xL);
    split3(y, yH, yM, yL);
    split3(z, zH, zM, zL);
    split3(pp, pH, pM, pL);
    uint4 q0 = make_uint4(pk(xH,xM), pk(xH,xL), pk(xH,xM), pk(yH,yM));
    uint4 q1 = make_uint4(pk(yH,yL), pk(yH,yM), pk(zH,zM), pk(zH,zL));
    uint4 q2 = make_uint4(pk(zH,zM), pk(ONE,ONE), pk(ONE,pH), pk(pM,pL));
    *(uint4*)(base +   0) = q0;
    *(uint4*)(base + 256) = q1;
    *(uint4*)(base + 512) = q2;
}

// ---------------------------------------------------------------------------
// 2x2 tile group: 16 MFMAs, min3-paired reductions (~1 VALU op per element).
// Col partials: full-wave LDS atomicMin into colh[col][hi] — idx = col*4+hi,
// so a wave's 64 lanes land 2/bank (free per bank-conflict model) vs 4/bank
// for the [hi][col] layout. Math + layouts HW-verified (rounds 1-5, absmax 0).
// ---------------------------------------------------------------------------
__device__ __forceinline__ void tile_pair(
    const bf16x8 (&af)[ITILES], bf16x8 b0, bf16x8 b1,
    f32x4 (&rmin)[ITILES], unsigned int* colh, int cbase,
    const f32x4& zf)
{
    f32x4 cp0 = {3e38f, 3e38f, 3e38f, 3e38f};
    f32x4 cp1 = {3e38f, 3e38f, 3e38f, 3e38f};
#pragma unroll
    for (int it = 0; it < ITILES; it += 2) {
        f32x4 d00 = __builtin_amdgcn_mfma_f32_16x16x32_bf16(af[it],     b0, zf, 0, 0, 0);
        f32x4 d01 = __builtin_amdgcn_mfma_f32_16x16x32_bf16(af[it],     b1, zf, 0, 0, 0);
        f32x4 d10 = __builtin_amdgcn_mfma_f32_16x16x32_bf16(af[it + 1], b0, zf, 0, 0, 0);
        f32x4 d11 = __builtin_amdgcn_mfma_f32_16x16x32_bf16(af[it + 1], b1, zf, 0, 0, 0);
#pragma unroll
        for (int r = 0; r < 4; ++r) {
            rmin[it][r]     = fminf(fminf(d00[r], d01[r]), rmin[it][r]);     // min3
            rmin[it + 1][r] = fminf(fminf(d10[r], d11[r]), rmin[it + 1][r]); // min3
            cp0[r]          = fminf(fminf(d00[r], d10[r]), cp0[r]);          // min3
            cp1[r]          = fminf(fminf(d01[r], d11[r]), cp1[r]);          // min3
        }
    }
    float c0 = fminf(fminf(cp0[0], cp0[1]), fminf(cp0[2], cp0[3]));
    float c1 = fminf(fminf(cp1[0], cp1[1]), fminf(cp1[2], cp1[3]));
    c0 = fmaxf(c0, 0.f);                 // bit-pattern uint-min == float-min
    c1 = fmaxf(c1, 0.f);
    atomicMin(&colh[cbase],      __float_as_uint(c0));
    atomicMin(&colh[cbase + 64], __float_as_uint(c1));   // +16 cols * 4
}

// ---------------------------------------------------------------------------
// Fused kernel, round-6 changes:
//  (a) T14 hoist: ALL global loads (A rows + B cols) issued at kernel top
//      into registers; encode phases are pure VALU->LDS (no load latency
//      inside barrier-fenced phases).
//  (b) Wave-local A staging: each wave writes/reads its own 8 KB bB region,
//      so no barrier between A-encode and A-readback (wave-synchronous LDS).
//  (c) colh transposed to [col][hi] -> inner-loop atomics 2-way (free).
// LDS = bB 32 KB + colh 8 KB = 40960 B -> 4 blocks/CU.
// ---------------------------------------------------------------------------
__global__ __launch_bounds__(256, 4) void chamfer_fused(
    const float* __restrict__ pred, const float* __restrict__ target,
    float* __restrict__ rowpart, float* __restrict__ colpart,
    float* __restrict__ out, const float* __restrict__ bpp,
    const float* __restrict__ lamda)
{
    __shared__ short bB[JT * 512];               // 32768 B (A-stage reuses it)
    __shared__ unsigned int colh[CHUNK * 4];     // 8192 B: [col][hi]

    const int tid  = threadIdx.x;
    const int lane = tid & 63;
    const int w    = tid >> 6;
    const int bid  = blockIdx.x;
    const int ck   = bid & (CHUNKS - 1);
    const int rb   = (bid >> 4) & (ROWBLKS - 1);
    const int b    = bid >> 8;

    const int col0 = ck * CHUNK;
    const float* asrc = pred   + (size_t)b * NPTS * 3;
    const float* bsrc = target + (size_t)b * NPTS * 3;

    // ---- T14: issue every global load now; latency hides under colh init
    //      + A encode + A readback (~all-VALU/DS work).
    const int ag0 = rb * ROWS_PER_BLOCK + w * ROWS_PER_WAVE + lane;  // row, this wave
    const int ag1 = ag0 + 64;
    float a0x = asrc[3 * ag0 + 0], a0y = asrc[3 * ag0 + 1], a0z = asrc[3 * ag0 + 2];
    float a1x = asrc[3 * ag1 + 0], a1y = asrc[3 * ag1 + 1], a1z = asrc[3 * ag1 + 2];
    const int bg0 = col0 + tid;
    const int bg1 = bg0 + 256;
    float b0x = bsrc[3 * bg0 + 0], b0y = bsrc[3 * bg0 + 1], b0z = bsrc[3 * bg0 + 2];
    float b1x = bsrc[3 * bg1 + 0], b1y = bsrc[3 * bg1 + 1], b1z = bsrc[3 * bg1 + 2];

    if (bid == 0 && tid == 0) out[0] = lamda[0] * bpp[0];  // init for atomicAdd

    for (int i = tid; i < CHUNK * 4; i += 256) colh[i] = 0x7F7F7F7Fu;

    // ---- Phase 1: A-encode, wave-local 8 KB region (rows w*128+lane, +64).
    {
        char* wbase = (char*)bB + w * 8192 + (lane & 15) * 16;
        encA(a0x, a0y, a0z, wbase + (lane >> 4) * 1024);
        encA(a1x, a1y, a1z, wbase + (4 + (lane >> 4)) * 1024);
    }

    // ---- Phase 2: wave-local A readback (no __syncthreads needed — same
    //      wave wrote this region; compiler inserts lgkmcnt).
    bf16x8 af[ITILES];
    {
        const char* ab = (const char*)bB + w * 8192 + lane * 16;
#pragma unroll
        for (int it = 0; it < ITILES; ++it)
            af[it] = *(const bf16x8*)(ab + it * 1024);
    }
    __syncthreads();   // all waves done reading A before B overwrites bB

    // ---- Phase 3: B-encode from hoisted registers (pure VALU -> LDS)
    encB(b0x, b0y, b0z, (char*)bB + (bg0 - col0 >> 4) * 1024 + ((bg0 - col0) & 15) * 16);
    encB(b1x, b1y, b1z, (char*)bB + (bg1 - col0 >> 4) * 1024 + ((bg1 - col0) & 15) * 16);

    f32x4 rmin[ITILES];
#pragma unroll
    for (int it = 0; it < ITILES; ++it) {
        rmin[it][0] = 3e38f; rmin[it][1] = 3e38f;
        rmin[it][2] = 3e38f; rmin[it][3] = 3e38f;
    }
    const f32x4 zf = {0.f, 0.f, 0.f, 0.f};

    __syncthreads();  // B encode + colh init visible

    // ---- Phase 4: main loop, sequential ds_read_b128, wrap-clamped prefetch
    const char* bb = (const char*)bB + lane * 16;
    bf16x8 B0 = *(const bf16x8*)(bb);
    bf16x8 B1 = *(const bf16x8*)(bb + 1024);
    int cbase = (lane & 15) * 4 + (lane >> 4);      // colh idx = col*4 + hi
    for (int jt = 0; jt < JT; jt += 2) {
        int nj = (jt + 2) & (JT - 1);                        // last iter wraps:
        bf16x8 Bn0 = *(const bf16x8*)(bb + nj * 1024);       // valid addr,
        bf16x8 Bn1 = *(const bf16x8*)(bb + (nj + 1) * 1024); // value unused
        tile_pair(af, B0, B1, rmin, colh, cbase, zf);
        cbase += 128;                                        // 32 cols * 4
        B0 = Bn0; B1 = Bn1;
    }

    // ---- row-min epilogue: shfl-reduce 16 col lanes, direct global store
#pragma unroll
    for (int it = 0; it < ITILES; ++it) {
#pragma unroll
        for (int r = 0; r < 4; ++r) {
            float v = rmin[it][r];
            v = fminf(v, __shfl_xor(v, 1, 64));
            v = fminf(v, __shfl_xor(v, 2, 64));
            v = fminf(v, __shfl_xor(v, 4, 64));
            v = fminf(v, __shfl_xor(v, 8, 64));
            if ((lane & 15) == 0) {
                int row = rb * ROWS_PER_BLOCK + w * ROWS_PER_WAVE
                        + it * 16 + (lane >> 4) * 4 + r;
                rowpart[((size_t)(b * CHUNKS) + ck) * NPTS + row] = fmaxf(v, 0.f);
            }
        }
    }

    // ---- col epilogue: merge 4 hi-groups (one uint4 read), coalesced store
    __syncthreads();
    for (int i = tid; i < CHUNK; i += 256) {
        uint4 v = *(const uint4*)&colh[i * 4];
        unsigned int m = umn(umn(v.x, v.y), umn(v.z, v.w));
        colpart[((size_t)(b * ROWBLKS) + rb) * NPTS + col0 + i] = __uint_as_float(m);
    }
}

// min over 16 slices per row/col cell, block-sum, one atomicAdd per block.
// out was initialized to lamda*bpp by chamfer_fused (stream-ordered).
__global__ __launch_bounds__(256) void reduce_partials(
    const float* __restrict__ rowpart, const float* __restrict__ colpart,
    float* __restrict__ out)
{
    const int tid = threadIdx.x;
    const int gt  = blockIdx.x * 256 + tid;    // 0..16383
    float s = 0.f;
#pragma unroll
    for (int a = 0; a < 2; a++) {
        const float* P = a ? colpart : rowpart;
#pragma unroll
        for (int cc = 0; cc < 2; cc++) {
            int c = gt + cc * 16384;           // 0..32767
            int b = c >> 13, r = c & 8191;
            const float* p = P + (size_t)b * 16 * NPTS + r;
            float m = p[0];
#pragma unroll
            for (int k = 1; k < 16; k++)
                m = fminf(m, p[(size_t)k * NPTS]);
            s += m;
        }
    }
#pragma unroll
    for (int off = 32; off > 0; off >>= 1) s += __shfl_down(s, off, 64);
    __shared__ float red[4];
    int lane = tid & 63, wid = tid >> 6;
    if (lane == 0) red[wid] = s;
    __syncthreads();
    if (tid == 0)
        atomicAdd(out, (red[0] + red[1] + red[2] + red[3]) * (1.0f / 32768.0f));
}

// ---------------------------------------------------------------------------
// Fallback: VALU kernel + atomic partmin (tiny workspace only)
// ---------------------------------------------------------------------------
#define T 256
#define Q 8
#define S 16
#define CH 512
#define NCOMBO 8

__global__ __launch_bounds__(T) void chamfer_partial(
    const float* __restrict__ pred, const float* __restrict__ target,
    unsigned int* __restrict__ partmin)
{
    __shared__ float4 db[CH + 2];

    const int bid   = blockIdx.x;
    const int dbc   = bid & (S - 1);
    const int qc    = (bid >> 4) & 3;
    const int combo = bid >> 6;
    const int dir   = combo & 1;
    const int b     = combo >> 1;

    const float* qptr = (dir == 0 ? pred : target) + (size_t)b * NPTS * 3;
    const float* dptr = (dir == 0 ? target : pred) + (size_t)b * NPTS * 3;

    const int tid = threadIdx.x;

    for (int p = tid; p < CH; p += T) {
        int gj = dbc * CH + p;
        float x = dptr[gj * 3 + 0];
        float y = dptr[gj * 3 + 1];
        float z = dptr[gj * 3 + 2];
        db[p] = make_float4(-2.f * x, -2.f * y, -2.f * z,
                            x * x + y * y + z * z);
    }

    float qx[Q], qy[Q], qz[Q], m[Q];
    int qi0 = qc * (T * Q) + tid;
#pragma unroll
    for (int k = 0; k < Q; k++) {
        int qi = qi0 + k * T;
        qx[k] = qptr[qi * 3 + 0];
        qy[k] = qptr[qi * 3 + 1];
        qz[k] = qptr[qi * 3 + 2];
        m[k]  = 3.4e38f;
    }
    __syncthreads();

    float4 c0 = db[0], c1 = db[1];
    for (int j = 0; j < CH; j += 2) {
        float4 n0 = db[j + 2];
        float4 n1 = db[j + 3];
#pragma unroll
        for (int k = 0; k < Q; k++) {
            float s0 = fmaf(c0.x, qx[k], fmaf(c0.y, qy[k], fmaf(c0.z, qz[k], c0.w)));
            float s1 = fmaf(c1.x, qx[k], fmaf(c1.y, qy[k], fmaf(c1.z, qz[k], c1.w)));
            m[k] = fminf(m[k], fminf(s0, s1));
        }
        c0 = n0; c1 = n1;
    }

#pragma unroll
    for (int k = 0; k < Q; k++) {
        int qi = qi0 + k * T;
        float qq = fmaf(qx[k], qx[k], fmaf(qy[k], qy[k], qz[k] * qz[k]));
        float d2 = fmaxf(m[k] + qq, 0.0f);
        atomicMin(&partmin[combo * NPTS + qi], __float_as_uint(d2));
    }
}

__global__ __launch_bounds__(1024) void reduce_final(
    const unsigned int* __restrict__ partmin,
    const float* __restrict__ bpp, const float* __restrict__ lamda,
    float* __restrict__ out)
{
    const int tid = threadIdx.x;
    float s = 0.f;
#pragma unroll
    for (int k = 0; k < (NCOMBO * NPTS) / 1024; k++)
        s += __uint_as_float(partmin[tid + k * 1024]);

#pragma unroll
    for (int off = 32; off > 0; off >>= 1)
        s += __shfl_down(s, off, 64);

    __shared__ float red[16];
    int lane = tid & 63, wid = tid >> 6;
    if (lane == 0) red[wid] = s;
    __syncthreads();
    if (wid == 0) {
        s = (lane < 16) ? red[lane] : 0.f;
#pragma unroll
        for (int off = 8; off > 0; off >>= 1)
            s += __shfl_down(s, off, 64);
        if (lane == 0)
            out[0] = s * (1.0f / 32768.0f) + lamda[0] * bpp[0];
    }
}

extern "C" void kernel_launch(void* const* d_in, const int* in_sizes, int n_in,
                              void* d_out, int out_size, void* d_ws, size_t ws_size,
                              hipStream_t stream) {
    const float* pred   = (const float*)d_in[0];
    const float* target = (const float*)d_in[1];
    const float* bpp    = (const float*)d_in[2];
    const float* lamda  = (const float*)d_in[3];

    const size_t part_bytes = (size_t)NB * 16 * NPTS * sizeof(float);  // 2 MB

    if (ws_size >= 2 * part_bytes) {
        float* rowpart = (float*)d_ws;
        float* colpart = rowpart + (size_t)NB * 16 * NPTS;
        chamfer_fused<<<NB * ROWBLKS * CHUNKS, 256, 0, stream>>>(
            pred, target, rowpart, colpart, (float*)d_out, bpp, lamda);
        reduce_partials<<<64, 256, 0, stream>>>(rowpart, colpart, (float*)d_out);
    } else {
        unsigned int* partmin = (unsigned int*)d_ws;
        hipMemsetAsync(partmin, 0x7F, (size_t)NCOMBO * NPTS * sizeof(unsigned int),
                       stream);
        chamfer_partial<<<NCOMBO * 4 * S, T, 0, stream>>>(pred, target, partmin);
        reduce_final<<<1, 1024, 0, stream>>>(partmin, bpp, lamda, (float*)d_out);
    }
}

// Round 8
// 83.931 us; speedup vs baseline: 6.0633x; 1.0135x over previous
//
#include <hip/hip_runtime.h>

#define NPTS 8192
#define NB 4

// ---------------- fused-kernel configuration ----------------
#define WPB 8                               // waves per block (512 threads)
#define ITILES 4                            // 16-row MFMA tiles per wave
#define ROWS_PER_WAVE (ITILES * 16)         // 64
#define ROWS_PER_BLOCK (WPB * ROWS_PER_WAVE)// 512
#define CHUNK 512                           // cols per block
#define JT (CHUNK / 16)                     // 32 col tiles
#define CHUNKS (NPTS / CHUNK)               // 16
#define ROWBLKS (NPTS / ROWS_PER_BLOCK)     // 16

using bf16x8 = __attribute__((ext_vector_type(8))) short;
using f32x4  = __attribute__((ext_vector_type(4))) float;

// bf16 round-to-nearest-even, manual
__device__ __forceinline__ unsigned short bfb(float v) {
    unsigned int x = __float_as_uint(v);
    return (unsigned short)((x + 0x7FFFu + ((x >> 16) & 1u)) >> 16);
}
__device__ __forceinline__ float bff(unsigned short u) {
    return __uint_as_float(((unsigned int)u) << 16);
}
// 3-way bf16 split: v ~= H + M + L (captures full fp32 mantissa)
__device__ __forceinline__ void split3(float v, unsigned short& H,
                                       unsigned short& M, unsigned short& L) {
    H = bfb(v); float r = v - bff(H);
    M = bfb(r); L = bfb(r - bff(M));
}
__device__ __forceinline__ unsigned int pk(unsigned short lo, unsigned short hi) {
    return (unsigned int)lo | ((unsigned int)hi << 16);
}
__device__ __forceinline__ unsigned int umn(unsigned int a, unsigned int b) {
    return a < b ? a : b;
}

// A-side encode: slot pattern per coord [H H M H L M]; pp 18..20; ONE 21..23;
// quarter 3 zeros (covers K 24..31 for both operands).
__device__ __forceinline__ void encA(float x, float y, float z, char* base) {
    const unsigned short ONE = 0x3F80u;
    float pp = fmaf(x, x, fmaf(y, y, z * z));
    unsigned short xH,xM,xL, yH,yM,yL, zH,zM,zL, pH,pM,pL;
    split3(-2.f * x, xH, xM, xL);
    split3(-2.f * y, yH, yM, yL);
    split3(-2.f * z, zH, zM, zL);
    split3(pp, pH, pM, pL);
    uint4 q0 = make_uint4(pk(xH,xH), pk(xM,xH), pk(xL,xM), pk(yH,yH));
    uint4 q1 = make_uint4(pk(yM,yH), pk(yL,yM), pk(zH,zH), pk(zM,zH));
    uint4 q2 = make_uint4(pk(zL,zM), pk(pH,pM), pk(pL,ONE), pk(ONE,ONE));
    uint4 q3 = make_uint4(0u, 0u, 0u, 0u);
    *(uint4*)(base +   0) = q0;
    *(uint4*)(base + 256) = q1;
    *(uint4*)(base + 512) = q2;
    *(uint4*)(base + 768) = q3;
}
// B-side encode: slot pattern per coord [H M H L H M]; ONE 18..20; pp 21..23.
// Quarter 3 skipped (A side is zero there).
__device__ __forceinline__ void encB(float x, float y, float z, char* base) {
    const unsigned short ONE = 0x3F80u;
    float pp = fmaf(x, x, fmaf(y, y, z * z));
    unsigned short xH,xM,xL, yH,yM,yL, zH,zM,zL, pH,pM,pL;
    split3(x, xH, xM, xL);
    split3(y, yH, yM, yL);
    split3(z, zH, zM, zL);
    split3(pp, pH, pM, pL);
    uint4 q0 = make_uint4(pk(xH,xM), pk(xH,xL), pk(xH,xM), pk(yH,yM));
    uint4 q1 = make_uint4(pk(yH,yL), pk(yH,yM), pk(zH,zM), pk(zH,zL));
    uint4 q2 = make_uint4(pk(zH,zM), pk(ONE,ONE), pk(ONE,pH), pk(pM,pL));
    *(uint4*)(base +   0) = q0;
    *(uint4*)(base + 256) = q1;
    *(uint4*)(base + 512) = q2;
}

// ---------------------------------------------------------------------------
// 2x2 tile group, ITILES=4: 8 MFMAs + fminf folds (compiler may fuse to
// v_min3 — minnum semantics match; do NOT hand-write min3 asm: round-7
// showed inline asm reading MFMA results miscomputes (hazard/scheduling)).
// Col partials: full-wave LDS atomicMin into colh[col][hi] (2/bank = free).
// Math + layouts HW-verified (rounds 1-6, absmax 0.0).
// ---------------------------------------------------------------------------
__device__ __forceinline__ void tile_pair(
    const bf16x8 (&af)[ITILES], bf16x8 b0, bf16x8 b1,
    f32x4 (&rmin)[ITILES], unsigned int* colh, int cbase,
    const f32x4& zf)
{
    f32x4 cp0 = {3e38f, 3e38f, 3e38f, 3e38f};
    f32x4 cp1 = {3e38f, 3e38f, 3e38f, 3e38f};
#pragma unroll
    for (int it = 0; it < ITILES; it += 2) {
        f32x4 d00 = __builtin_amdgcn_mfma_f32_16x16x32_bf16(af[it],     b0, zf, 0, 0, 0);
        f32x4 d01 = __builtin_amdgcn_mfma_f32_16x16x32_bf16(af[it],     b1, zf, 0, 0, 0);
        f32x4 d10 = __builtin_amdgcn_mfma_f32_16x16x32_bf16(af[it + 1], b0, zf, 0, 0, 0);
        f32x4 d11 = __builtin_amdgcn_mfma_f32_16x16x32_bf16(af[it + 1], b1, zf, 0, 0, 0);
#pragma unroll
        for (int r = 0; r < 4; ++r) {
            rmin[it][r]     = fminf(fminf(d00[r], d01[r]), rmin[it][r]);
            rmin[it + 1][r] = fminf(fminf(d10[r], d11[r]), rmin[it + 1][r]);
            cp0[r]          = fminf(fminf(d00[r], d10[r]), cp0[r]);
            cp1[r]          = fminf(fminf(d01[r], d11[r]), cp1[r]);
        }
    }
    float c0 = fminf(fminf(cp0[0], cp0[1]), fminf(cp0[2], cp0[3]));
    float c1 = fminf(fminf(cp1[0], cp1[1]), fminf(cp1[2], cp1[3]));
    c0 = fmaxf(c0, 0.f);                 // bit-pattern uint-min == float-min
    c1 = fmaxf(c1, 0.f);
    atomicMin(&colh[cbase],      __float_as_uint(c0));
    atomicMin(&colh[cbase + 64], __float_as_uint(c1));   // +16 cols * 4
}

// ---------------------------------------------------------------------------
// Fused kernel, round-8 change: 8 waves x 64 rows (was 4 x 128). Per-wave
// register state halves (af 16 + rmin 16 vs 32+32) -> unified VGPR+AGPR
// budget ~75 (was ~128, which capped occupancy at 4 waves/SIMD, Occupancy
// ~40%). __launch_bounds__(512,6) targets 24 waves/CU without spill risk.
// Same 512x512 tile per block; LDS = bB 32 KB + colh 8 KB = 40960 B.
// ---------------------------------------------------------------------------
__global__ __launch_bounds__(512, 6) void chamfer_fused(
    const float* __restrict__ pred, const float* __restrict__ target,
    float* __restrict__ rowpart, float* __restrict__ colpart,
    float* __restrict__ out, const float* __restrict__ bpp,
    const float* __restrict__ lamda)
{
    __shared__ short bB[JT * 512];               // 32768 B (A-stage reuses it)
    __shared__ unsigned int colh[CHUNK * 4];     // 8192 B: [col][hi]

    const int tid  = threadIdx.x;
    const int lane = tid & 63;
    const int w    = tid >> 6;                   // 0..7
    const int bid  = blockIdx.x;
    const int ck   = bid & (CHUNKS - 1);
    const int rb   = (bid >> 4) & (ROWBLKS - 1);
    const int b    = bid >> 8;

    const int col0 = ck * CHUNK;
    const float* asrc = pred   + (size_t)b * NPTS * 3;
    const float* bsrc = target + (size_t)b * NPTS * 3;

    // ---- hoisted global loads: 1 A-row + 1 B-col per thread
    const int ag = rb * ROWS_PER_BLOCK + tid;    // == rb*512 + w*64 + lane
    float ax = asrc[3 * ag + 0], ay = asrc[3 * ag + 1], az = asrc[3 * ag + 2];
    const int bg = col0 + tid;
    float bx = bsrc[3 * bg + 0], by = bsrc[3 * bg + 1], bz = bsrc[3 * bg + 2];

    if (bid == 0 && tid == 0) out[0] = lamda[0] * bpp[0];  // init for atomicAdd

    for (int i = tid; i < CHUNK * 4; i += 512) colh[i] = 0x7F7F7F7Fu;

    // ---- Phase 1: A-encode, wave-local 4 KB region (row w*64+lane).
    //      tile = lane>>4, row-in-tile = lane&15.
    encA(ax, ay, az,
         (char*)bB + w * 4096 + (lane >> 4) * 1024 + (lane & 15) * 16);

    // ---- Phase 2: wave-local A readback (same wave wrote it; lgkmcnt only).
    //      Fragment addr: tile it, K-quarter lane>>4, row lane&15 ==
    //      it*1024 + lane*16 within the wave region.
    bf16x8 af[ITILES];
    {
        const char* ab = (const char*)bB + w * 4096 + lane * 16;
#pragma unroll
        for (int it = 0; it < ITILES; ++it)
            af[it] = *(const bf16x8*)(ab + it * 1024);
    }
    __syncthreads();   // all waves done reading A before B overwrites bB

    // ---- Phase 3: B-encode from hoisted registers (1 col per thread)
    encB(bx, by, bz, (char*)bB + (tid >> 4) * 1024 + (tid & 15) * 16);

    f32x4 rmin[ITILES];
#pragma unroll
    for (int it = 0; it < ITILES; ++it) {
        rmin[it][0] = 3e38f; rmin[it][1] = 3e38f;
        rmin[it][2] = 3e38f; rmin[it][3] = 3e38f;
    }
    const f32x4 zf = {0.f, 0.f, 0.f, 0.f};

    __syncthreads();  // B encode + colh init visible

    // ---- Phase 4: main loop, sequential ds_read_b128, wrap-clamped prefetch
    const char* bb = (const char*)bB + lane * 16;
    bf16x8 B0 = *(const bf16x8*)(bb);
    bf16x8 B1 = *(const bf16x8*)(bb + 1024);
    int cbase = (lane & 15) * 4 + (lane >> 4);      // colh idx = col*4 + hi
    for (int jt = 0; jt < JT; jt += 2) {
        int nj = (jt + 2) & (JT - 1);                        // last iter wraps:
        bf16x8 Bn0 = *(const bf16x8*)(bb + nj * 1024);       // valid addr,
        bf16x8 Bn1 = *(const bf16x8*)(bb + (nj + 1) * 1024); // value unused
        tile_pair(af, B0, B1, rmin, colh, cbase, zf);
        cbase += 128;                                        // 32 cols * 4
        B0 = Bn0; B1 = Bn1;
    }

    // ---- row-min epilogue: shfl-reduce 16 col lanes, direct global store
#pragma unroll
    for (int it = 0; it < ITILES; ++it) {
#pragma unroll
        for (int r = 0; r < 4; ++r) {
            float v = rmin[it][r];
            v = fminf(v, __shfl_xor(v, 1, 64));
            v = fminf(v, __shfl_xor(v, 2, 64));
            v = fminf(v, __shfl_xor(v, 4, 64));
            v = fminf(v, __shfl_xor(v, 8, 64));
            if ((lane & 15) == 0) {
                int row = rb * ROWS_PER_BLOCK + w * ROWS_PER_WAVE
                        + it * 16 + (lane >> 4) * 4 + r;
                rowpart[((size_t)(b * CHUNKS) + ck) * NPTS + row] = fmaxf(v, 0.f);
            }
        }
    }

    // ---- col epilogue: merge 4 hi-groups (one uint4 read), coalesced store
    __syncthreads();
    for (int i = tid; i < CHUNK; i += 512) {
        uint4 v = *(const uint4*)&colh[i * 4];
        unsigned int m = umn(umn(v.x, v.y), umn(v.z, v.w));
        colpart[((size_t)(b * ROWBLKS) + rb) * NPTS + col0 + i] = __uint_as_float(m);
    }
}

// min over 16 slices per row/col cell, block-sum, one atomicAdd per block.
// out was initialized to lamda*bpp by chamfer_fused (stream-ordered).
__global__ __launch_bounds__(256) void reduce_partials(
    const float* __restrict__ rowpart, const float* __restrict__ colpart,
    float* __restrict__ out)
{
    const int tid = threadIdx.x;
    const int gt  = blockIdx.x * 256 + tid;    // 0..16383
    float s = 0.f;
#pragma unroll
    for (int a = 0; a < 2; a++) {
        const float* P = a ? colpart : rowpart;
#pragma unroll
        for (int cc = 0; cc < 2; cc++) {
            int c = gt + cc * 16384;           // 0..32767
            int b = c >> 13, r = c & 8191;
            const float* p = P + (size_t)b * 16 * NPTS + r;
            float m = p[0];
#pragma unroll
            for (int k = 1; k < 16; k++)
                m = fminf(m, p[(size_t)k * NPTS]);
            s += m;
        }
    }
#pragma unroll
    for (int off = 32; off > 0; off >>= 1) s += __shfl_down(s, off, 64);
    __shared__ float red[4];
    int lane = tid & 63, wid = tid >> 6;
    if (lane == 0) red[wid] = s;
    __syncthreads();
    if (tid == 0)
        atomicAdd(out, (red[0] + red[1] + red[2] + red[3]) * (1.0f / 32768.0f));
}

// ---------------------------------------------------------------------------
// Fallback: VALU kernel + atomic partmin (tiny workspace only)
// ---------------------------------------------------------------------------
#define T 256
#define Q 8
#define S 16
#define CH 512
#define NCOMBO 8

__global__ __launch_bounds__(T) void chamfer_partial(
    const float* __restrict__ pred, const float* __restrict__ target,
    unsigned int* __restrict__ partmin)
{
    __shared__ float4 db[CH + 2];

    const int bid   = blockIdx.x;
    const int dbc   = bid & (S - 1);
    const int qc    = (bid >> 4) & 3;
    const int combo = bid >> 6;
    const int dir   = combo & 1;
    const int b     = combo >> 1;

    const float* qptr = (dir == 0 ? pred : target) + (size_t)b * NPTS * 3;
    const float* dptr = (dir == 0 ? target : pred) + (size_t)b * NPTS * 3;

    const int tid = threadIdx.x;

    for (int p = tid; p < CH; p += T) {
        int gj = dbc * CH + p;
        float x = dptr[gj * 3 + 0];
        float y = dptr[gj * 3 + 1];
        float z = dptr[gj * 3 + 2];
        db[p] = make_float4(-2.f * x, -2.f * y, -2.f * z,
                            x * x + y * y + z * z);
    }

    float qx[Q], qy[Q], qz[Q], m[Q];
    int qi0 = qc * (T * Q) + tid;
#pragma unroll
    for (int k = 0; k < Q; k++) {
        int qi = qi0 + k * T;
        qx[k] = qptr[qi * 3 + 0];
        qy[k] = qptr[qi * 3 + 1];
        qz[k] = qptr[qi * 3 + 2];
        m[k]  = 3.4e38f;
    }
    __syncthreads();

    float4 c0 = db[0], c1 = db[1];
    for (int j = 0; j < CH; j += 2) {
        float4 n0 = db[j + 2];
        float4 n1 = db[j + 3];
#pragma unroll
        for (int k = 0; k < Q; k++) {
            float s0 = fmaf(c0.x, qx[k], fmaf(c0.y, qy[k], fmaf(c0.z, qz[k], c0.w)));
            float s1 = fmaf(c1.x, qx[k], fmaf(c1.y, qy[k], fmaf(c1.z, qz[k], c1.w)));
            m[k] = fminf(m[k], fminf(s0, s1));
        }
        c0 = n0; c1 = n1;
    }

#pragma unroll
    for (int k = 0; k < Q; k++) {
        int qi = qi0 + k * T;
        float qq = fmaf(qx[k], qx[k], fmaf(qy[k], qy[k], qz[k] * qz[k]));
        float d2 = fmaxf(m[k] + qq, 0.0f);
        atomicMin(&partmin[combo * NPTS + qi], __float_as_uint(d2));
    }
}

__global__ __launch_bounds__(1024) void reduce_final(
    const unsigned int* __restrict__ partmin,
    const float* __restrict__ bpp, const float* __restrict__ lamda,
    float* __restrict__ out)
{
    const int tid = threadIdx.x;
    float s = 0.f;
#pragma unroll
    for (int k = 0; k < (NCOMBO * NPTS) / 1024; k++)
        s += __uint_as_float(partmin[tid + k * 1024]);

#pragma unroll
    for (int off = 32; off > 0; off >>= 1)
        s += __shfl_down(s, off, 64);

    __shared__ float red[16];
    int lane = tid & 63, wid = tid >> 6;
    if (lane == 0) red[wid] = s;
    __syncthreads();
    if (wid == 0) {
        s = (lane < 16) ? red[lane] : 0.f;
#pragma unroll
        for (int off = 8; off > 0; off >>= 1)
            s += __shfl_down(s, off, 64);
        if (lane == 0)
            out[0] = s * (1.0f / 32768.0f) + lamda[0] * bpp[0];
    }
}

extern "C" void kernel_launch(void* const* d_in, const int* in_sizes, int n_in,
                              void* d_out, int out_size, void* d_ws, size_t ws_size,
                              hipStream_t stream) {
    const float* pred   = (const float*)d_in[0];
    const float* target = (const float*)d_in[1];
    const float* bpp    = (const float*)d_in[2];
    const float* lamda  = (const float*)d_in[3];

    const size_t part_bytes = (size_t)NB * 16 * NPTS * sizeof(float);  // 2 MB

    if (ws_size >= 2 * part_bytes) {
        float* rowpart = (float*)d_ws;
        float* colpart = rowpart + (size_t)NB * 16 * NPTS;
        chamfer_fused<<<NB * ROWBLKS * CHUNKS, 512, 0, stream>>>(
            pred, target, rowpart, colpart, (float*)d_out, bpp, lamda);
        reduce_partials<<<64, 256, 0, stream>>>(rowpart, colpart, (float*)d_out);
    } else {
        unsigned int* partmin = (unsigned int*)d_ws;
        hipMemsetAsync(partmin, 0x7F, (size_t)NCOMBO * NPTS * sizeof(unsigned int),
                       stream);
        chamfer_partial<<<NCOMBO * 4 * S, T, 0, stream>>>(pred, target, partmin);
        reduce_final<<<1, 1024, 0, stream>>>(partmin, bpp, lamda, (float*)d_out);
    }
}

// Round 9
// 82.538 us; speedup vs baseline: 6.1656x; 1.0169x over previous
//
#include <hip/hip_runtime.h>

#define NPTS 8192
#define NB 4

// ---------------- fused-kernel configuration ----------------
#define WPB 8                               // waves per block (512 threads)
#define ITILES 4                            // 16-row MFMA tiles per wave
#define ROWS_PER_WAVE (ITILES * 16)         // 64
#define ROWS_PER_BLOCK (WPB * ROWS_PER_WAVE)// 512
#define CHUNK 512                           // cols per block
#define JT (CHUNK / 16)                     // 32 col tiles
#define CHUNKS (NPTS / CHUNK)               // 16
#define ROWBLKS (NPTS / ROWS_PER_BLOCK)     // 16

using bf16x8 = __attribute__((ext_vector_type(8))) short;
using f32x4  = __attribute__((ext_vector_type(4))) float;

// bf16 round-to-nearest-even, manual
__device__ __forceinline__ unsigned short bfb(float v) {
    unsigned int x = __float_as_uint(v);
    return (unsigned short)((x + 0x7FFFu + ((x >> 16) & 1u)) >> 16);
}
__device__ __forceinline__ float bff(unsigned short u) {
    return __uint_as_float(((unsigned int)u) << 16);
}
// 3-way bf16 split: v ~= H + M + L (captures full fp32 mantissa)
__device__ __forceinline__ void split3(float v, unsigned short& H,
                                       unsigned short& M, unsigned short& L) {
    H = bfb(v); float r = v - bff(H);
    M = bfb(r); L = bfb(r - bff(M));
}
__device__ __forceinline__ unsigned int pk(unsigned short lo, unsigned short hi) {
    return (unsigned int)lo | ((unsigned int)hi << 16);
}
__device__ __forceinline__ unsigned int umn(unsigned int a, unsigned int b) {
    return a < b ? a : b;
}

// A-side encode: slot pattern per coord [H H M H L M]; pp 18..20; ONE 21..23;
// quarter 3 zeros (covers K 24..31 for both operands).
__device__ __forceinline__ void encA(float x, float y, float z, char* base) {
    const unsigned short ONE = 0x3F80u;
    float pp = fmaf(x, x, fmaf(y, y, z * z));
    unsigned short xH,xM,xL, yH,yM,yL, zH,zM,zL, pH,pM,pL;
    split3(-2.f * x, xH, xM, xL);
    split3(-2.f * y, yH, yM, yL);
    split3(-2.f * z, zH, zM, zL);
    split3(pp, pH, pM, pL);
    uint4 q0 = make_uint4(pk(xH,xH), pk(xM,xH), pk(xL,xM), pk(yH,yH));
    uint4 q1 = make_uint4(pk(yM,yH), pk(yL,yM), pk(zH,zH), pk(zM,zH));
    uint4 q2 = make_uint4(pk(zL,zM), pk(pH,pM), pk(pL,ONE), pk(ONE,ONE));
    uint4 q3 = make_uint4(0u, 0u, 0u, 0u);
    *(uint4*)(base +   0) = q0;
    *(uint4*)(base + 256) = q1;
    *(uint4*)(base + 512) = q2;
    *(uint4*)(base + 768) = q3;
}
// B-side encode: slot pattern per coord [H M H L H M]; ONE 18..20; pp 21..23.
// Quarter 3 skipped (A side is zero there).
__device__ __forceinline__ void encB(float x, float y, float z, char* base) {
    const unsigned short ONE = 0x3F80u;
    float pp = fmaf(x, x, fmaf(y, y, z * z));
    unsigned short xH,xM,xL, yH,yM,yL, zH,zM,zL, pH,pM,pL;
    split3(x, xH, xM, xL);
    split3(y, yH, yM, yL);
    split3(z, zH, zM, zL);
    split3(pp, pH, pM, pL);
    uint4 q0 = make_uint4(pk(xH,xM), pk(xH,xL), pk(xH,xM), pk(yH,yM));
    uint4 q1 = make_uint4(pk(yH,yL), pk(yH,yM), pk(zH,zM), pk(zH,zL));
    uint4 q2 = make_uint4(pk(zH,zM), pk(ONE,ONE), pk(ONE,pH), pk(pM,pL));
    *(uint4*)(base +   0) = q0;
    *(uint4*)(base + 256) = q1;
    *(uint4*)(base + 512) = q2;
}

// ---------------------------------------------------------------------------
// 2x2 tile group, ITILES=4: 8 MFMAs + fminf folds. Col partials: full-wave
// LDS atomicMin into colh[col][hi] (64 distinct addrs, 2/bank = free).
// Math + layouts HW-verified (rounds 1-8, absmax 0.0).
// ---------------------------------------------------------------------------
__device__ __forceinline__ void tile_pair(
    const bf16x8 (&af)[ITILES], bf16x8 b0, bf16x8 b1,
    f32x4 (&rmin)[ITILES], unsigned int* colh, int cbase,
    const f32x4& zf)
{
    f32x4 cp0 = {3e38f, 3e38f, 3e38f, 3e38f};
    f32x4 cp1 = {3e38f, 3e38f, 3e38f, 3e38f};
#pragma unroll
    for (int it = 0; it < ITILES; it += 2) {
        f32x4 d00 = __builtin_amdgcn_mfma_f32_16x16x32_bf16(af[it],     b0, zf, 0, 0, 0);
        f32x4 d01 = __builtin_amdgcn_mfma_f32_16x16x32_bf16(af[it],     b1, zf, 0, 0, 0);
        f32x4 d10 = __builtin_amdgcn_mfma_f32_16x16x32_bf16(af[it + 1], b0, zf, 0, 0, 0);
        f32x4 d11 = __builtin_amdgcn_mfma_f32_16x16x32_bf16(af[it + 1], b1, zf, 0, 0, 0);
#pragma unroll
        for (int r = 0; r < 4; ++r) {
            rmin[it][r]     = fminf(fminf(d00[r], d01[r]), rmin[it][r]);
            rmin[it + 1][r] = fminf(fminf(d10[r], d11[r]), rmin[it + 1][r]);
            cp0[r]          = fminf(fminf(d00[r], d10[r]), cp0[r]);
            cp1[r]          = fminf(fminf(d01[r], d11[r]), cp1[r]);
        }
    }
    float c0 = fminf(fminf(cp0[0], cp0[1]), fminf(cp0[2], cp0[3]));
    float c1 = fminf(fminf(cp1[0], cp1[1]), fminf(cp1[2], cp1[3]));
    c0 = fmaxf(c0, 0.f);                 // bit-pattern uint-min == float-min
    c1 = fmaxf(c1, 0.f);
    atomicMin(&colh[cbase],      __float_as_uint(c0));
    atomicMin(&colh[cbase + 64], __float_as_uint(c1));   // +16 cols * 4
}

// ---------------------------------------------------------------------------
// Fused kernel, round-9 change: ROW-MIN EPILOGUE REWORK. The old epilogue's
// 64 __shfl_xor per wave are ds_bpermute ops — DS pipe, equal to the entire
// main loop's DS load (2048 ops/CU, invariant across rounds 6/8 — matching
// their perf flatness). New: stage rmin through bB (dead after main loop),
// wave-local, 2 passes of 32 rows x 16 cols at row-stride 80 B (writes
// 2/bank free; 16B-aligned b128 readback), VALU fold + 1 shfl per pass,
// coalesced rowpart stores. 64 shfls + 16 scattered stores ->
// 16 writes + 4 reads + 2 shfls + coalesced stores.
// ---------------------------------------------------------------------------
__global__ __launch_bounds__(512, 6) void chamfer_fused(
    const float* __restrict__ pred, const float* __restrict__ target,
    float* __restrict__ rowpart, float* __restrict__ colpart,
    float* __restrict__ out, const float* __restrict__ bpp,
    const float* __restrict__ lamda)
{
    __shared__ short bB[JT * 512];               // 32768 B (A-stage + epilogue reuse)
    __shared__ unsigned int colh[CHUNK * 4];     // 8192 B: [col][hi]

    const int tid  = threadIdx.x;
    const int lane = tid & 63;
    const int w    = tid >> 6;                   // 0..7
    const int bid  = blockIdx.x;
    const int ck   = bid & (CHUNKS - 1);
    const int rb   = (bid >> 4) & (ROWBLKS - 1);
    const int b    = bid >> 8;

    const int col0 = ck * CHUNK;
    const float* asrc = pred   + (size_t)b * NPTS * 3;
    const float* bsrc = target + (size_t)b * NPTS * 3;

    // ---- hoisted global loads: 1 A-row + 1 B-col per thread
    const int ag = rb * ROWS_PER_BLOCK + tid;    // == rb*512 + w*64 + lane
    float ax = asrc[3 * ag + 0], ay = asrc[3 * ag + 1], az = asrc[3 * ag + 2];
    const int bg = col0 + tid;
    float bx = bsrc[3 * bg + 0], by = bsrc[3 * bg + 1], bz = bsrc[3 * bg + 2];

    if (bid == 0 && tid == 0) out[0] = lamda[0] * bpp[0];  // init for atomicAdd

    for (int i = tid; i < CHUNK * 4; i += 512) colh[i] = 0x7F7F7F7Fu;

    // ---- Phase 1: A-encode, wave-local 4 KB region (row w*64+lane).
    encA(ax, ay, az,
         (char*)bB + w * 4096 + (lane >> 4) * 1024 + (lane & 15) * 16);

    // ---- Phase 2: wave-local A readback (same wave wrote it; lgkmcnt only)
    bf16x8 af[ITILES];
    {
        const char* ab = (const char*)bB + w * 4096 + lane * 16;
#pragma unroll
        for (int it = 0; it < ITILES; ++it)
            af[it] = *(const bf16x8*)(ab + it * 1024);
    }
    __syncthreads();   // all waves done reading A before B overwrites bB

    // ---- Phase 3: B-encode from hoisted registers (1 col per thread)
    encB(bx, by, bz, (char*)bB + (tid >> 4) * 1024 + (tid & 15) * 16);

    f32x4 rmin[ITILES];
#pragma unroll
    for (int it = 0; it < ITILES; ++it) {
        rmin[it][0] = 3e38f; rmin[it][1] = 3e38f;
        rmin[it][2] = 3e38f; rmin[it][3] = 3e38f;
    }
    const f32x4 zf = {0.f, 0.f, 0.f, 0.f};

    __syncthreads();  // B encode + colh init visible

    // ---- Phase 4: main loop, sequential ds_read_b128, wrap-clamped prefetch
    const char* bb = (const char*)bB + lane * 16;
    bf16x8 B0 = *(const bf16x8*)(bb);
    bf16x8 B1 = *(const bf16x8*)(bb + 1024);
    int cbase = (lane & 15) * 4 + (lane >> 4);      // colh idx = col*4 + hi
    for (int jt = 0; jt < JT; jt += 2) {
        int nj = (jt + 2) & (JT - 1);                        // last iter wraps:
        bf16x8 Bn0 = *(const bf16x8*)(bb + nj * 1024);       // valid addr,
        bf16x8 Bn1 = *(const bf16x8*)(bb + (nj + 1) * 1024); // value unused
        tile_pair(af, B0, B1, rmin, colh, cbase, zf);
        cbase += 128;                                        // 32 cols * 4
        B0 = Bn0; B1 = Bn1;
    }

    __syncthreads();   // main loop done: bB (B-tiles) dead, colh complete

    // ---- row-min epilogue: stage rmin through bB, wave-local, 2 passes.
    //      Pass p covers tiles {2p,2p+1} = 32 rows. Layout: row32*80 + col*4
    //      (stride 80 B: write banks (row32*20+col)%32 -> hi pairs split
    //      across 16-bank halves, 2 lanes/bank = free; 80 is 16B-aligned
    //      so readback is legal ds_read_b128).
    {
        char* sb = (char*)bB + w * 2560;          // 8 waves x 2560 = 20 KB
        const int hi = lane >> 4, col = lane & 15;
#pragma unroll
        for (int p = 0; p < 2; ++p) {
#pragma unroll
            for (int halfit = 0; halfit < 2; ++halfit) {
#pragma unroll
                for (int r = 0; r < 4; ++r) {
                    int row32 = halfit * 16 + hi * 4 + r;
                    *(float*)(sb + row32 * 80 + col * 4) = rmin[p * 2 + halfit][r];
                }
            }
            // wave-local write->read of same region: in-order LDS
            const int a = lane >> 1, bsel = lane & 1;
            const char* rp = sb + a * 80 + bsel * 32;
            f32x4 v0 = *(const f32x4*)(rp);
            f32x4 v1 = *(const f32x4*)(rp + 16);
            float v = fminf(fminf(fminf(v0[0], v0[1]), fminf(v0[2], v0[3])),
                            fminf(fminf(v1[0], v1[1]), fminf(v1[2], v1[3])));
            v = fminf(v, __shfl_xor(v, 1, 64));
            if (bsel == 0) {
                int row = rb * ROWS_PER_BLOCK + w * ROWS_PER_WAVE + p * 32 + a;
                rowpart[((size_t)(b * CHUNKS) + ck) * NPTS + row] = fmaxf(v, 0.f);
            }
            // pin pass-1 writes after pass-0 reads (region reuse; rule-18
            // family: don't let the scheduler float LDS ops across)
            __builtin_amdgcn_sched_barrier(0);
        }
    }

    // ---- col epilogue: merge 4 hi-groups (one uint4 read), coalesced store
    for (int i = tid; i < CHUNK; i += 512) {
        uint4 v = *(const uint4*)&colh[i * 4];
        unsigned int m = umn(umn(v.x, v.y), umn(v.z, v.w));
        colpart[((size_t)(b * ROWBLKS) + rb) * NPTS + col0 + i] = __uint_as_float(m);
    }
}

// min over 16 slices per row/col cell, block-sum, one atomicAdd per block.
// out was initialized to lamda*bpp by chamfer_fused (stream-ordered).
__global__ __launch_bounds__(256) void reduce_partials(
    const float* __restrict__ rowpart, const float* __restrict__ colpart,
    float* __restrict__ out)
{
    const int tid = threadIdx.x;
    const int gt  = blockIdx.x * 256 + tid;    // 0..16383
    float s = 0.f;
#pragma unroll
    for (int a = 0; a < 2; a++) {
        const float* P = a ? colpart : rowpart;
#pragma unroll
        for (int cc = 0; cc < 2; cc++) {
            int c = gt + cc * 16384;           // 0..32767
            int b = c >> 13, r = c & 8191;
            const float* p = P + (size_t)b * 16 * NPTS + r;
            float m = p[0];
#pragma unroll
            for (int k = 1; k < 16; k++)
                m = fminf(m, p[(size_t)k * NPTS]);
            s += m;
        }
    }
#pragma unroll
    for (int off = 32; off > 0; off >>= 1) s += __shfl_down(s, off, 64);
    __shared__ float red[4];
    int lane = tid & 63, wid = tid >> 6;
    if (lane == 0) red[wid] = s;
    __syncthreads();
    if (tid == 0)
        atomicAdd(out, (red[0] + red[1] + red[2] + red[3]) * (1.0f / 32768.0f));
}

// ---------------------------------------------------------------------------
// Fallback: VALU kernel + atomic partmin (tiny workspace only)
// ---------------------------------------------------------------------------
#define T 256
#define Q 8
#define S 16
#define CH 512
#define NCOMBO 8

__global__ __launch_bounds__(T) void chamfer_partial(
    const float* __restrict__ pred, const float* __restrict__ target,
    unsigned int* __restrict__ partmin)
{
    __shared__ float4 db[CH + 2];

    const int bid   = blockIdx.x;
    const int dbc   = bid & (S - 1);
    const int qc    = (bid >> 4) & 3;
    const int combo = bid >> 6;
    const int dir   = combo & 1;
    const int b     = combo >> 1;

    const float* qptr = (dir == 0 ? pred : target) + (size_t)b * NPTS * 3;
    const float* dptr = (dir == 0 ? target : pred) + (size_t)b * NPTS * 3;

    const int tid = threadIdx.x;

    for (int p = tid; p < CH; p += T) {
        int gj = dbc * CH + p;
        float x = dptr[gj * 3 + 0];
        float y = dptr[gj * 3 + 1];
        float z = dptr[gj * 3 + 2];
        db[p] = make_float4(-2.f * x, -2.f * y, -2.f * z,
                            x * x + y * y + z * z);
    }

    float qx[Q], qy[Q], qz[Q], m[Q];
    int qi0 = qc * (T * Q) + tid;
#pragma unroll
    for (int k = 0; k < Q; k++) {
        int qi = qi0 + k * T;
        qx[k] = qptr[qi * 3 + 0];
        qy[k] = qptr[qi * 3 + 1];
        qz[k] = qptr[qi * 3 + 2];
        m[k]  = 3.4e38f;
    }
    __syncthreads();

    float4 c0 = db[0], c1 = db[1];
    for (int j = 0; j < CH; j += 2) {
        float4 n0 = db[j + 2];
        float4 n1 = db[j + 3];
#pragma unroll
        for (int k = 0; k < Q; k++) {
            float s0 = fmaf(c0.x, qx[k], fmaf(c0.y, qy[k], fmaf(c0.z, qz[k], c0.w)));
            float s1 = fmaf(c1.x, qx[k], fmaf(c1.y, qy[k], fmaf(c1.z, qz[k], c1.w)));
            m[k] = fminf(m[k], fminf(s0, s1));
        }
        c0 = n0; c1 = n1;
    }

#pragma unroll
    for (int k = 0; k < Q; k++) {
        int qi = qi0 + k * T;
        float qq = fmaf(qx[k], qx[k], fmaf(qy[k], qy[k], qz[k] * qz[k]));
        float d2 = fmaxf(m[k] + qq, 0.0f);
        atomicMin(&partmin[combo * NPTS + qi], __float_as_uint(d2));
    }
}

__global__ __launch_bounds__(1024) void reduce_final(
    const unsigned int* __restrict__ partmin,
    const float* __restrict__ bpp, const float* __restrict__ lamda,
    float* __restrict__ out)
{
    const int tid = threadIdx.x;
    float s = 0.f;
#pragma unroll
    for (int k = 0; k < (NCOMBO * NPTS) / 1024; k++)
        s += __uint_as_float(partmin[tid + k * 1024]);

#pragma unroll
    for (int off = 32; off > 0; off >>= 1)
        s += __shfl_down(s, off, 64);

    __shared__ float red[16];
    int lane = tid & 63, wid = tid >> 6;
    if (lane == 0) red[wid] = s;
    __syncthreads();
    if (wid == 0) {
        s = (lane < 16) ? red[lane] : 0.f;
#pragma unroll
        for (int off = 8; off > 0; off >>= 1)
            s += __shfl_down(s, off, 64);
        if (lane == 0)
            out[0] = s * (1.0f / 32768.0f) + lamda[0] * bpp[0];
    }
}

extern "C" void kernel_launch(void* const* d_in, const int* in_sizes, int n_in,
                              void* d_out, int out_size, void* d_ws, size_t ws_size,
                              hipStream_t stream) {
    const float* pred   = (const float*)d_in[0];
    const float* target = (const float*)d_in[1];
    const float* bpp    = (const float*)d_in[2];
    const float* lamda  = (const float*)d_in[3];

    const size_t part_bytes = (size_t)NB * 16 * NPTS * sizeof(float);  // 2 MB

    if (ws_size >= 2 * part_bytes) {
        float* rowpart = (float*)d_ws;
        float* colpart = rowpart + (size_t)NB * 16 * NPTS;
        chamfer_fused<<<NB * ROWBLKS * CHUNKS, 512, 0, stream>>>(
            pred, target, rowpart, colpart, (float*)d_out, bpp, lamda);
        reduce_partials<<<64, 256, 0, stream>>>(rowpart, colpart, (float*)d_out);
    } else {
        unsigned int* partmin = (unsigned int*)d_ws;
        hipMemsetAsync(partmin, 0x7F, (size_t)NCOMBO * NPTS * sizeof(unsigned int),
                       stream);
        chamfer_partial<<<NCOMBO * 4 * S, T, 0, stream>>>(pred, target, partmin);
        reduce_final<<<1, 1024, 0, stream>>>(partmin, bpp, lamda, (float*)d_out);
    }
}